// Round 1
// baseline (2349.211 us; speedup 1.0000x reference)
//
#include <hip/hip_runtime.h>
#include <cstdint>

#define TPB 256

__device__ __forceinline__ float silu_f(float x) {
  return x / (1.f + __expf(-x));
}

// wT[(tap*Cin + c)*Cout + o] = w[(o*Cin + c)*taps + tap]
__global__ void k_transpose_w(const float* __restrict__ w, float* __restrict__ wT,
                              int Cout, int Cin, int taps) {
  int e = blockIdx.x * TPB + threadIdx.x;
  int total = Cout * Cin * taps;
  if (e >= total) return;
  int o = e / (Cin * taps);
  int r = e - o * (Cin * taps);
  int c = r / taps;
  int tap = r - c * taps;
  wT[(tap * Cin + c) * Cout + o] = w[e];
}

// bilinear 16x16 -> 64x64, half-pixel centers, edge clamp (matches jax.image.resize)
__global__ void k_upsample(const float* __restrict__ in, float* __restrict__ out) {
  int idx = blockIdx.x * TPB + threadIdx.x;
  if (idx >= 8 * 256 * 64 * 64) return;
  int x = idx & 63;
  int y = (idx >> 6) & 63;
  int bc = idx >> 12;
  float sy = (y + 0.5f) * 0.25f - 0.5f;
  float sx = (x + 0.5f) * 0.25f - 0.5f;
  float y0f = floorf(sy), x0f = floorf(sx);
  float ly = sy - y0f, lx = sx - x0f;
  int y0 = (int)y0f, x0 = (int)x0f;
  int y0c = min(15, max(0, y0)), y1c = min(15, max(0, y0 + 1));
  int x0c = min(15, max(0, x0)), x1c = min(15, max(0, x0 + 1));
  const float* src = in + bc * 256;
  float v00 = src[y0c * 16 + x0c], v01 = src[y0c * 16 + x1c];
  float v10 = src[y1c * 16 + x0c], v11 = src[y1c * 16 + x1c];
  out[idx] = (1.f - ly) * ((1.f - lx) * v00 + lx * v01)
           + ly * ((1.f - lx) * v10 + lx * v11);
}

// generic direct conv as tap-wise tiled GEMM. Block: 64 out-ch x 64 px (one row).
// in = concat(in1[0:Csplit], in2[Csplit:Cin]) along channels. taps = 1 or 9 (pad=taps==9).
__global__ __launch_bounds__(256) void k_conv(const float* __restrict__ in1,
    const float* __restrict__ in2, int Csplit, int Cin, int Cout, int taps,
    const float* __restrict__ wT, const float* __restrict__ bias,
    float* __restrict__ out) {
  const int y = blockIdx.x;
  const int O0 = blockIdx.y * 64;
  const int b = blockIdx.z;
  const int t = threadIdx.x;
  const int tx = t & 15;   // pixel group (4 px each)
  const int ty = t >> 4;   // out-ch group (4 o each)
  __shared__ float wl[32][64];
  __shared__ float il[32][64];
  float acc[4][4];
  #pragma unroll
  for (int i = 0; i < 4; ++i)
    #pragma unroll
    for (int j = 0; j < 4; ++j) acc[i][j] = 0.f;
  const int pd = (taps == 9) ? 1 : 0;
  for (int tap = 0; tap < taps; ++tap) {
    const int dy = tap / 3 - pd;
    const int dx = tap % 3 - pd;
    const int yin = y + dy;
    if (yin < 0 || yin >= 64) continue;  // block-uniform
    for (int c0 = 0; c0 < Cin; c0 += 32) {
      __syncthreads();
      #pragma unroll
      for (int i = 0; i < 8; ++i) {
        int e = t + i * TPB;
        int oo = e & 63, cc = e >> 6;
        int o = O0 + oo;
        wl[cc][oo] = (o < Cout) ? wT[(tap * Cin + c0 + cc) * Cout + o] : 0.f;
      }
      #pragma unroll
      for (int i = 0; i < 8; ++i) {
        int e = t + i * TPB;
        int pp = e & 63, cc = e >> 6;
        int c = c0 + cc;
        int xin = pp + dx;
        float v = 0.f;
        if (xin >= 0 && xin < 64) {
          const float* src; int cl, nch;
          if (c < Csplit) { src = in1; cl = c; nch = Csplit; }
          else            { src = in2; cl = c - Csplit; nch = Cin - Csplit; }
          v = src[((b * nch + cl) * 64 + yin) * 64 + xin];
        }
        il[cc][pp] = v;
      }
      __syncthreads();
      #pragma unroll
      for (int cc = 0; cc < 32; ++cc) {
        float4 wv = *(const float4*)&wl[cc][ty * 4];
        float4 iv = *(const float4*)&il[cc][tx * 4];
        float wa[4] = {wv.x, wv.y, wv.z, wv.w};
        float ia[4] = {iv.x, iv.y, iv.z, iv.w};
        #pragma unroll
        for (int i = 0; i < 4; ++i)
          #pragma unroll
          for (int j = 0; j < 4; ++j) acc[i][j] += wa[i] * ia[j];
      }
    }
  }
  #pragma unroll
  for (int i = 0; i < 4; ++i) {
    int o = O0 + ty * 4 + i;
    if (o < Cout) {
      float bv = bias[o];
      float4 r;
      r.x = acc[i][0] + bv; r.y = acc[i][1] + bv;
      r.z = acc[i][2] + bv; r.w = acc[i][3] + bv;
      *(float4*)&out[((b * Cout + o) * 64 + y) * 64 + tx * 4] = r;
    }
  }
}

// depthwise 7x7, pad 3
__global__ __launch_bounds__(256) void k_dwconv7(const float* __restrict__ in,
    const float* __restrict__ w, const float* __restrict__ bias,
    float* __restrict__ out) {
  const int c = blockIdx.x, b = blockIdx.y;
  __shared__ float tile[70][70];
  __shared__ float wk[49];
  const int t = threadIdx.x;
  const float* src = in + (b * 256 + c) * 4096;
  for (int e = t; e < 4900; e += TPB) {
    int r = e / 70, q = e - r * 70;
    int yy = r - 3, xx = q - 3;
    tile[r][q] = (yy >= 0 && yy < 64 && xx >= 0 && xx < 64) ? src[yy * 64 + xx] : 0.f;
  }
  if (t < 49) wk[t] = w[c * 49 + t];
  __syncthreads();
  const float bv = bias[c];
  float* dst = out + (b * 256 + c) * 4096;
  for (int e = t; e < 4096; e += TPB) {
    int yy = e >> 6, xx = e & 63;
    float s = bv;
    #pragma unroll
    for (int dy = 0; dy < 7; ++dy)
      #pragma unroll
      for (int dx = 0; dx < 7; ++dx)
        s += tile[yy + dy][xx + dx] * wk[dy * 7 + dx];
    dst[e] = s;
  }
}

// GroupNorm(32 groups, eps 1e-6) + SiLU. One block per (b, group): 8 ch x 4096 px.
__global__ __launch_bounds__(256) void k_gn_silu(const float* __restrict__ in,
    float* __restrict__ out, const float* __restrict__ gamma,
    const float* __restrict__ beta) {
  const int bg = blockIdx.x;
  const int b = bg >> 5, g = bg & 31;
  const float4* src = (const float4*)(in + (size_t)(b * 256 + g * 8) * 4096);
  float4* dst = (float4*)(out + (size_t)(b * 256 + g * 8) * 4096);
  const int t = threadIdx.x;
  float s = 0.f, sq = 0.f;
  for (int e = t; e < 8192; e += TPB) {
    float4 v = src[e];
    s += v.x + v.y + v.z + v.w;
    sq += v.x * v.x + v.y * v.y + v.z * v.z + v.w * v.w;
  }
  #pragma unroll
  for (int off = 32; off > 0; off >>= 1) {
    s += __shfl_down(s, off);
    sq += __shfl_down(sq, off);
  }
  __shared__ float ps[4], pq[4];
  __shared__ float smv, srv;
  const int wid = t >> 6, lane = t & 63;
  if (lane == 0) { ps[wid] = s; pq[wid] = sq; }
  __syncthreads();
  if (t == 0) {
    float S = ps[0] + ps[1] + ps[2] + ps[3];
    float Q = pq[0] + pq[1] + pq[2] + pq[3];
    float mean = S * (1.f / 32768.f);
    float var = Q * (1.f / 32768.f) - mean * mean;
    smv = mean;
    srv = rsqrtf(var + 1e-6f);
  }
  __syncthreads();
  const float m = smv, rs = srv;
  for (int e = t; e < 8192; e += TPB) {
    float4 v = src[e];
    int c = g * 8 + (e >> 10);
    float ga = gamma[c] * rs;
    float be = beta[c] - m * ga;
    float a0 = v.x * ga + be;
    float a1 = v.y * ga + be;
    float a2 = v.z * ga + be;
    float a3 = v.w * ga + be;
    v.x = silu_f(a0); v.y = silu_f(a1); v.z = silu_f(a2); v.w = silu_f(a3);
    dst[e] = v;
  }
}

// Deformable conv v2: dg=8, K=9, Cpg=32, stride1 pad1, zero border, torchvision layout.
// co: [B,216,H,W] = [off_y/off_x interleaved per (g,k) : 144][mask logits : 72]
// Block: one (b, row). 256 out-ch x 64 px. Per (g,k): stage 32x256 weight chunk +
// 32x64 sampled activations (c-major) into LDS, 8x8 register-blocked MAC.
__global__ __launch_bounds__(256) void k_dcn(const float* __restrict__ x,
    const float* __restrict__ co, const float* __restrict__ wT,
    const float* __restrict__ bias, float* __restrict__ out) {
  const int y = blockIdx.x;
  const int b = blockIdx.y;
  const int t = threadIdx.x;
  const int wave = t >> 6, lane = t & 63;
  const int lo = lane >> 3, lp = lane & 7;
  const int obase = wave * 64 + lo * 8;
  const int pbase = lp * 8;
  __shared__ float s2[32][72];   // [c][px], padded
  __shared__ float wl[8192];     // [c][o] for current (g,k)
  float acc[8][8];
  #pragma unroll
  for (int i = 0; i < 8; ++i)
    #pragma unroll
    for (int j = 0; j < 8; ++j) acc[i][j] = 0.f;
  const int cpx = lane;        // sampling phase: this thread's pixel
  const int cc0 = wave * 8;    // sampling phase: this thread's 8 channels
  const float* cob = co + ((size_t)b * 216 * 64 + y) * 64 + cpx;
  for (int g = 0; g < 8; ++g) {
    for (int k = 0; k < 9; ++k) {
      __syncthreads();
      #pragma unroll
      for (int i = 0; i < 32; ++i) {
        int e = t + i * TPB;
        wl[e] = wT[((k * 256) + g * 32 + (e >> 8)) * 256 + (e & 255)];
      }
      {
        float offy = cob[(size_t)(g * 18 + 2 * k) * 4096];
        float offx = cob[(size_t)(g * 18 + 2 * k + 1) * 4096];
        float mv = cob[(size_t)(144 + g * 9 + k) * 4096];
        mv = 1.f / (1.f + __expf(-mv));
        float py = offy + (float)(y - 1 + k / 3);
        float px = offx + (float)(cpx - 1 + k % 3);
        float y0f = floorf(py), x0f = floorf(px);
        float ly = py - y0f, lx = px - x0f;
        int y0 = (int)y0f, x0 = (int)x0f;
        int y1 = y0 + 1, x1 = x0 + 1;
        float fy0 = (y0 >= 0 && y0 < 64) ? 1.f : 0.f;
        float fy1 = (y1 >= 0 && y1 < 64) ? 1.f : 0.f;
        float fx0 = (x0 >= 0 && x0 < 64) ? 1.f : 0.f;
        float fx1 = (x1 >= 0 && x1 < 64) ? 1.f : 0.f;
        float w00 = (1.f - ly) * (1.f - lx) * fy0 * fx0 * mv;
        float w01 = (1.f - ly) * lx * fy0 * fx1 * mv;
        float w10 = ly * (1.f - lx) * fy1 * fx0 * mv;
        float w11 = ly * lx * fy1 * fx1 * mv;
        int y0c = min(63, max(0, y0)), y1c = min(63, max(0, y1));
        int x0c = min(63, max(0, x0)), x1c = min(63, max(0, x1));
        int i00 = y0c * 64 + x0c, i01 = y0c * 64 + x1c;
        int i10 = y1c * 64 + x0c, i11 = y1c * 64 + x1c;
        const float* xb = x + (size_t)(b * 256 + g * 32 + cc0) * 4096;
        #pragma unroll
        for (int cc = 0; cc < 8; ++cc) {
          const float* xc = xb + cc * 4096;
          s2[cc0 + cc][cpx] = w00 * xc[i00] + w01 * xc[i01]
                            + w10 * xc[i10] + w11 * xc[i11];
        }
      }
      __syncthreads();
      #pragma unroll
      for (int c = 0; c < 32; ++c) {
        float4 w0 = *(const float4*)&wl[c * 256 + obase];
        float4 w1v = *(const float4*)&wl[c * 256 + obase + 4];
        float4 p0 = *(const float4*)&s2[c][pbase];
        float4 p1 = *(const float4*)&s2[c][pbase + 4];
        float wa[8] = {w0.x, w0.y, w0.z, w0.w, w1v.x, w1v.y, w1v.z, w1v.w};
        float pa[8] = {p0.x, p0.y, p0.z, p0.w, p1.x, p1.y, p1.z, p1.w};
        #pragma unroll
        for (int i = 0; i < 8; ++i)
          #pragma unroll
          for (int j = 0; j < 8; ++j)
            acc[i][j] += wa[i] * pa[j];
      }
    }
  }
  #pragma unroll
  for (int i = 0; i < 8; ++i) {
    int o = obase + i;
    float bv = bias[o];
    float4 r0, r1;
    r0.x = acc[i][0] + bv; r0.y = acc[i][1] + bv;
    r0.z = acc[i][2] + bv; r0.w = acc[i][3] + bv;
    r1.x = acc[i][4] + bv; r1.y = acc[i][5] + bv;
    r1.z = acc[i][6] + bv; r1.w = acc[i][7] + bv;
    float* op = out + ((size_t)(b * 256 + o) * 64 + y) * 64 + pbase;
    *(float4*)op = r0;
    *(float4*)(op + 4) = r1;
  }
}

extern "C" void kernel_launch(void* const* d_in, const int* in_sizes, int n_in,
                              void* d_out, int out_size, void* d_ws, size_t ws_size,
                              hipStream_t stream) {
  const float* main_f = (const float*)d_in[0];
  const float* cond   = (const float*)d_in[1];
  const float* w1  = (const float*)d_in[2];
  const float* b1  = (const float*)d_in[3];
  const float* g1  = (const float*)d_in[4];
  const float* be1 = (const float*)d_in[5];
  const float* w2  = (const float*)d_in[6];
  const float* b2  = (const float*)d_in[7];
  const float* g2  = (const float*)d_in[8];
  const float* be2 = (const float*)d_in[9];
  const float* w3  = (const float*)d_in[10];
  const float* b3  = (const float*)d_in[11];
  const float* w4  = (const float*)d_in[12];
  const float* b4  = (const float*)d_in[13];
  const float* g3  = (const float*)d_in[14];
  const float* be3 = (const float*)d_in[15];
  const float* w_co  = (const float*)d_in[16];
  const float* b_co  = (const float*)d_in[17];
  const float* w_dcn = (const float*)d_in[18];
  const float* b_dcn = (const float*)d_in[19];

  float* out = (float*)d_out;
  float* warp_out = out;               // [8,256,64,64]
  float* offset_feat = out + 8388608;  // [8,256,64,64]

  float* ws = (float*)d_ws;
  float* bufA  = ws;                   // 8388608 floats
  float* bufB  = bufA + 8388608;       // 8388608 floats
  float* wT1   = bufB + 8388608;       // 512*256   = 131072
  float* wT3   = wT1 + 131072;         // 256*256   = 65536
  float* wT4   = wT3 + 65536;          // 256*256*9 = 589824
  float* wTco  = wT4 + 589824;         // 9*256*216 = 497664
  float* wTdcn = wTco + 497664;        // 256*256*9 = 589824

  auto cdiv = [](int a, int b) { return (a + b - 1) / b; };

  k_transpose_w<<<cdiv(256 * 512, TPB), TPB, 0, stream>>>(w1, wT1, 256, 512, 1);
  k_transpose_w<<<cdiv(256 * 256, TPB), TPB, 0, stream>>>(w3, wT3, 256, 256, 1);
  k_transpose_w<<<cdiv(256 * 256 * 9, TPB), TPB, 0, stream>>>(w4, wT4, 256, 256, 9);
  k_transpose_w<<<cdiv(216 * 256 * 9, TPB), TPB, 0, stream>>>(w_co, wTco, 216, 256, 9);
  k_transpose_w<<<cdiv(256 * 256 * 9, TPB), TPB, 0, stream>>>(w_dcn, wTdcn, 256, 256, 9);

  k_upsample<<<cdiv(8 * 256 * 4096, TPB), TPB, 0, stream>>>(cond, bufA);

  dim3 g256(64, 4, 8);
  // conv1: 1x1 over concat(cond_up, main): 512 -> 256
  k_conv<<<g256, TPB, 0, stream>>>(bufA, main_f, 256, 512, 256, 1, wT1, b1, bufB);
  k_gn_silu<<<256, TPB, 0, stream>>>(bufB, bufB, g1, be1);
  dim3 gdw(256, 8);
  k_dwconv7<<<gdw, TPB, 0, stream>>>(bufB, w2, b2, bufA);
  k_gn_silu<<<256, TPB, 0, stream>>>(bufA, bufA, g2, be2);
  // conv3: 1x1 256->256
  k_conv<<<g256, TPB, 0, stream>>>(bufA, nullptr, 256, 256, 256, 1, wT3, b3, bufB);
  // conv4: 3x3 256->256
  k_conv<<<g256, TPB, 0, stream>>>(bufB, nullptr, 256, 256, 256, 9, wT4, b4, bufA);
  // GN3 + SiLU -> offset_feat (second output)
  k_gn_silu<<<256, TPB, 0, stream>>>(bufA, offset_feat, g3, be3);
  // conv_offset: 3x3 256->216
  dim3 gco(64, 4, 8);
  k_conv<<<gco, TPB, 0, stream>>>(offset_feat, nullptr, 256, 256, 216, 9, wTco, b_co, bufB);
  // deformable conv -> warp (first output)
  dim3 gdcn(64, 8);
  k_dcn<<<gdcn, TPB, 0, stream>>>(main_f, bufB, wTdcn, b_dcn, warp_out);
}

// Round 3
// 1025.930 us; speedup vs baseline: 2.2898x; 2.2898x over previous
//
#include <hip/hip_runtime.h>
#include <cstdint>

#define TPB 256

typedef __attribute__((ext_vector_type(8))) short s16x8;
typedef __attribute__((ext_vector_type(4))) short s16x4;
typedef __attribute__((ext_vector_type(4))) float f32x4;

__device__ __forceinline__ float silu_f(float x) { return x / (1.f + __expf(-x)); }

__device__ __forceinline__ short f2bf(float f) {
  union { float f; unsigned u; } v; v.f = f;
  unsigned r = v.u + 0x7fffu + ((v.u >> 16) & 1u);
  return (short)(r >> 16);
}
__device__ __forceinline__ float bf2f(short s) {
  union { unsigned u; float f; } v;
  v.u = ((unsigned)(unsigned short)s) << 16;
  return v.f;
}

// Pre-arrange conv weights into MFMA A-fragment order (bf16).
// src w: [Cout][Cin][taps] (OIHW flat). dst elem ((q*16 + ot)*64 + l)*8 + j =
//   bf16(w[o = ot*16 + (l&15)][c = cb*32 + ((l>>4)&3)*8 + j][tap]), zero-padded.
// mode 0: q = tap*ncb + cb ; mode 1 (dcn): q = cb*9 + tap.
__global__ void k_prep_w(const float* __restrict__ w, short* __restrict__ dst,
                         int Cout, int Cin, int taps, int nq, int mode) {
  int idx = blockIdx.x * TPB + threadIdx.x;
  int total = nq * 16 * 64 * 8;
  if (idx >= total) return;
  int j = idx & 7;
  int l = (idx >> 3) & 63;
  int ot = (idx >> 9) & 15;
  int q = idx >> 13;
  int tap, cb;
  if (mode == 0) { int ncb = Cin >> 5; tap = q / ncb; cb = q - tap * ncb; }
  else           { tap = q % 9; cb = q / 9; }
  int o = ot * 16 + (l & 15);
  int c = cb * 32 + ((l >> 4) & 3) * 8 + j;
  float v = 0.f;
  if (o < Cout && c < Cin) v = w[((size_t)o * Cin + c) * taps + tap];
  dst[idx] = f2bf(v);
}

__global__ void k_tobf16(const float* __restrict__ in, short* __restrict__ out, int n4) {
  int i = blockIdx.x * TPB + threadIdx.x;
  if (i >= n4) return;
  float4 v = ((const float4*)in)[i];
  s16x4 r;
  r[0] = f2bf(v.x); r[1] = f2bf(v.y); r[2] = f2bf(v.z); r[3] = f2bf(v.w);
  ((s16x4*)out)[i] = r;
}

// bilinear 16x16 -> 64x64, half-pixel centers, edge clamp -> bf16
__global__ void k_upsample(const float* __restrict__ in, short* __restrict__ out) {
  int idx = blockIdx.x * TPB + threadIdx.x;
  if (idx >= 8 * 256 * 64 * 64) return;
  int x = idx & 63;
  int y = (idx >> 6) & 63;
  int bc = idx >> 12;
  float sy = (y + 0.5f) * 0.25f - 0.5f;
  float sx = (x + 0.5f) * 0.25f - 0.5f;
  float y0f = floorf(sy), x0f = floorf(sx);
  float ly = sy - y0f, lx = sx - x0f;
  int y0 = (int)y0f, x0 = (int)x0f;
  int y0c = min(15, max(0, y0)), y1c = min(15, max(0, y0 + 1));
  int x0c = min(15, max(0, x0)), x1c = min(15, max(0, x0 + 1));
  const float* src = in + bc * 256;
  float v00 = src[y0c * 16 + x0c], v01 = src[y0c * 16 + x1c];
  float v10 = src[y1c * 16 + x0c], v11 = src[y1c * 16 + x1c];
  float r = (1.f - ly) * ((1.f - lx) * v00 + lx * v01)
          + ly * ((1.f - lx) * v10 + lx * v11);
  out[idx] = f2bf(r);
}

// MFMA conv: block = (row y, 64 out-ch group og, batch b), 4 waves in 2x2
// (o-half x px-half), each wave 32o x 32px via 2x2 tiles of 16x16x32.
// Input = concat(in1[0:Csplit], in2[Csplit:Cin]) bf16. taps = 1 or 9 (pad=1).
// LDS tile s2[pp][cc]: pp = px_in+1 (0..65), stride 40 shorts (80B -> 2-way banks),
// staged once per (dy, cb) and reused for dx = -1/0/1 via shifted reads.
__global__ __launch_bounds__(256) void k_conv_mfma(
    const short* __restrict__ in1, const short* __restrict__ in2,
    int Csplit, int Cin, int Cout, int taps,
    const short* __restrict__ wf, const float* __restrict__ bias,
    short* __restrict__ out_bf, float* __restrict__ out_f32) {
  const int y = blockIdx.x, og = blockIdx.y, b = blockIdx.z;
  const int t = threadIdx.x;
  const int wid = t >> 6, l = t & 63;
  const int wo = wid >> 1, wp = wid & 1;
  const int ncb = Cin >> 5;
  __shared__ __align__(16) short s2[66 * 40];
  f32x4 acc[2][2];
  #pragma unroll
  for (int i = 0; i < 2; ++i)
    #pragma unroll
    for (int j = 0; j < 2; ++j) acc[i][j] = (f32x4){0.f, 0.f, 0.f, 0.f};
  const int ndy = (taps == 9) ? 3 : 1;
  for (int idy = 0; idy < ndy; ++idy) {
    const int dy = (taps == 9) ? idy - 1 : 0;
    const int yin = y + dy;
    if (yin < 0 || yin >= 64) continue;  // block-uniform; zero-pad rows contribute 0
    for (int cb = 0; cb < ncb; ++cb) {
      __syncthreads();
      {
        int cc = t & 31, part = t >> 5;  // 8 parts x 9 px cover px_in -1..70 (clip 64)
        int c = cb * 32 + cc;
        const short* src;
        if (c < Csplit) src = in1 + ((size_t)(b * Csplit + c) * 64 + yin) * 64;
        else src = in2 + ((size_t)(b * (Cin - Csplit) + (c - Csplit)) * 64 + yin) * 64;
        #pragma unroll
        for (int i = 0; i < 9; ++i) {
          int pxin = part * 9 - 1 + i;
          if (pxin <= 64) {
            short v = 0;
            if (pxin >= 0 && pxin < 64) v = src[pxin];
            s2[(pxin + 1) * 40 + cc] = v;
          }
        }
      }
      __syncthreads();
      for (int idx_ = 0; idx_ < ndy; ++idx_) {
        const int dx = (taps == 9) ? idx_ - 1 : 0;
        const int tap = (taps == 9) ? (dy + 1) * 3 + (dx + 1) : 0;
        const int q = tap * ncb + cb;
        s16x8 afr[2], bfr[2];
        #pragma unroll
        for (int i = 0; i < 2; ++i) {
          int ot = og * 4 + wo * 2 + i;
          afr[i] = *(const s16x8*)(wf + (((size_t)q * 16 + ot) * 64 + l) * 8);
        }
        #pragma unroll
        for (int jt = 0; jt < 2; ++jt) {
          int px = wp * 32 + jt * 16 + (l & 15);
          bfr[jt] = *(const s16x8*)(&s2[(px + dx + 1) * 40 + (l >> 4) * 8]);
        }
        #pragma unroll
        for (int i = 0; i < 2; ++i)
          #pragma unroll
          for (int jt = 0; jt < 2; ++jt)
            acc[i][jt] = __builtin_amdgcn_mfma_f32_16x16x32_bf16(
                afr[i], bfr[jt], acc[i][jt], 0, 0, 0);
      }
    }
  }
  #pragma unroll
  for (int i = 0; i < 2; ++i) {
    #pragma unroll
    for (int jt = 0; jt < 2; ++jt) {
      int px = wp * 32 + jt * 16 + (l & 15);
      int obase = og * 64 + wo * 32 + i * 16 + (l >> 4) * 4;
      #pragma unroll
      for (int r = 0; r < 4; ++r) {
        int o = obase + r;
        if (o < Cout) {
          float v = acc[i][jt][r] + bias[o];
          size_t oidx = (((size_t)b * Cout + o) * 64 + y) * 64 + px;
          if (out_bf) out_bf[oidx] = f2bf(v);
          if (out_f32) out_f32[oidx] = v;
        }
      }
    }
  }
}

// depthwise 7x7, pad 3, bf16 in/out, f32 math
__global__ __launch_bounds__(256) void k_dwconv7(const short* __restrict__ in,
    const float* __restrict__ w, const float* __restrict__ bias,
    short* __restrict__ out) {
  const int c = blockIdx.x, b = blockIdx.y;
  __shared__ float tile[70][70];
  __shared__ float wk[49];
  const int t = threadIdx.x;
  const short* src = in + (size_t)(b * 256 + c) * 4096;
  for (int e = t; e < 4900; e += TPB) {
    int r = e / 70, q = e - r * 70;
    int yy = r - 3, xx = q - 3;
    tile[r][q] = (yy >= 0 && yy < 64 && xx >= 0 && xx < 64) ? bf2f(src[yy * 64 + xx]) : 0.f;
  }
  if (t < 49) wk[t] = w[c * 49 + t];
  __syncthreads();
  const float bv = bias[c];
  short* dst = out + (size_t)(b * 256 + c) * 4096;
  for (int e = t; e < 4096; e += TPB) {
    int yy = e >> 6, xx = e & 63;
    float s = bv;
    #pragma unroll
    for (int dy = 0; dy < 7; ++dy)
      #pragma unroll
      for (int dx = 0; dx < 7; ++dx)
        s += tile[yy + dy][xx + dx] * wk[dy * 7 + dx];
    dst[e] = f2bf(s);
  }
}

// GroupNorm(32,eps 1e-6)+SiLU, bf16 in, bf16 out (+ optional f32 out). In-place safe.
__global__ __launch_bounds__(256) void k_gn_silu_bf(const short* __restrict__ in,
    short* __restrict__ out_bf, float* __restrict__ out_f32,
    const float* __restrict__ gamma, const float* __restrict__ beta) {
  const int bg = blockIdx.x;
  const int b = bg >> 5, g = bg & 31;
  const size_t base = (size_t)(b * 256 + g * 8) * 4096;
  const s16x8* src = (const s16x8*)(in + base);
  const int t = threadIdx.x;
  float s = 0.f, sq = 0.f;
  for (int e = t; e < 4096; e += TPB) {
    s16x8 v = src[e];
    #pragma unroll
    for (int j = 0; j < 8; ++j) { float f = bf2f(v[j]); s += f; sq += f * f; }
  }
  #pragma unroll
  for (int off = 32; off > 0; off >>= 1) {
    s += __shfl_down(s, off);
    sq += __shfl_down(sq, off);
  }
  __shared__ float ps[4], pq[4];
  __shared__ float smv, srv;
  const int wid = t >> 6, lane = t & 63;
  if (lane == 0) { ps[wid] = s; pq[wid] = sq; }
  __syncthreads();
  if (t == 0) {
    float S = ps[0] + ps[1] + ps[2] + ps[3];
    float Q = pq[0] + pq[1] + pq[2] + pq[3];
    float mean = S * (1.f / 32768.f);
    float var = Q * (1.f / 32768.f) - mean * mean;
    smv = mean;
    srv = rsqrtf(var + 1e-6f);
  }
  __syncthreads();
  const float m = smv, rs = srv;
  for (int e = t; e < 4096; e += TPB) {
    s16x8 v = src[e];
    int c = g * 8 + (e >> 9);
    float ga = gamma[c] * rs;
    float be = beta[c] - m * ga;
    s16x8 r;
    #pragma unroll
    for (int j = 0; j < 8; ++j) {
      float a = bf2f(v[j]) * ga + be;
      float o = silu_f(a);
      r[j] = f2bf(o);
      if (out_f32) out_f32[base + (size_t)e * 8 + j] = o;
    }
    ((s16x8*)(out_bf + base))[e] = r;
  }
}

// Deformable conv v2 via MFMA. Block = (row y, batch b); 4 waves, wave w owns
// o in [w*64, w*64+64) x all 64 px -> 4x4 tiles of 16x16. K-chunks = (g,k) pairs.
// Sampling (verified round-0 math) -> bf16 -> LDS s2[px][cc] (stride 40 shorts).
__global__ __launch_bounds__(256) void k_dcn_mfma(const short* __restrict__ xbf,
    const short* __restrict__ co, const short* __restrict__ wf,
    const float* __restrict__ bias, float* __restrict__ out) {
  const int y = blockIdx.x, b = blockIdx.y;
  const int t = threadIdx.x;
  const int wid = t >> 6, l = t & 63;
  __shared__ __align__(16) short s2[64 * 40];
  f32x4 acc[4][4];
  #pragma unroll
  for (int i = 0; i < 4; ++i)
    #pragma unroll
    for (int j = 0; j < 4; ++j) acc[i][j] = (f32x4){0.f, 0.f, 0.f, 0.f};
  const int px = l;
  const int cc0 = wid * 8;
  const short* cob = co + ((size_t)b * 216 * 64 + y) * 64 + px;
  for (int g = 0; g < 8; ++g) {
    const short* xb = xbf + (size_t)(b * 256 + g * 32 + cc0) * 4096;
    for (int k = 0; k < 9; ++k) {
      __syncthreads();
      {
        float offy = bf2f(cob[(size_t)(g * 18 + 2 * k) * 4096]);
        float offx = bf2f(cob[(size_t)(g * 18 + 2 * k + 1) * 4096]);
        float mlog = bf2f(cob[(size_t)(144 + g * 9 + k) * 4096]);
        float mv = 1.f / (1.f + __expf(-mlog));
        float py = offy + (float)(y - 1 + k / 3);
        float pxf = offx + (float)(px - 1 + k % 3);
        float y0f = floorf(py), x0f = floorf(pxf);
        float ly = py - y0f, lx = pxf - x0f;
        int y0 = (int)y0f, x0 = (int)x0f;
        int y1 = y0 + 1, x1 = x0 + 1;
        float fy0 = (y0 >= 0 && y0 < 64) ? 1.f : 0.f;
        float fy1 = (y1 >= 0 && y1 < 64) ? 1.f : 0.f;
        float fx0 = (x0 >= 0 && x0 < 64) ? 1.f : 0.f;
        float fx1 = (x1 >= 0 && x1 < 64) ? 1.f : 0.f;
        float w00 = (1.f - ly) * (1.f - lx) * fy0 * fx0 * mv;
        float w01 = (1.f - ly) * lx * fy0 * fx1 * mv;
        float w10 = ly * (1.f - lx) * fy1 * fx0 * mv;
        float w11 = ly * lx * fy1 * fx1 * mv;
        int y0c = min(63, max(0, y0)), y1c = min(63, max(0, y1));
        int x0c = min(63, max(0, x0)), x1c = min(63, max(0, x1));
        int i00 = y0c * 64 + x0c, i01 = y0c * 64 + x1c;
        int i10 = y1c * 64 + x0c, i11 = y1c * 64 + x1c;
        s16x8 pk;
        #pragma unroll
        for (int cc = 0; cc < 8; ++cc) {
          const short* xc = xb + cc * 4096;
          float v = w00 * bf2f(xc[i00]) + w01 * bf2f(xc[i01])
                  + w10 * bf2f(xc[i10]) + w11 * bf2f(xc[i11]);
          pk[cc] = f2bf(v);
        }
        *(s16x8*)(&s2[px * 40 + cc0]) = pk;
      }
      __syncthreads();
      const int q = g * 9 + k;
      s16x8 afr[4], bfr[4];
      #pragma unroll
      for (int i = 0; i < 4; ++i)
        afr[i] = *(const s16x8*)(wf + (((size_t)q * 16 + wid * 4 + i) * 64 + l) * 8);
      #pragma unroll
      for (int jt = 0; jt < 4; ++jt)
        bfr[jt] = *(const s16x8*)(&s2[(jt * 16 + (l & 15)) * 40 + (l >> 4) * 8]);
      #pragma unroll
      for (int i = 0; i < 4; ++i)
        #pragma unroll
        for (int jt = 0; jt < 4; ++jt)
          acc[i][jt] = __builtin_amdgcn_mfma_f32_16x16x32_bf16(
              afr[i], bfr[jt], acc[i][jt], 0, 0, 0);
    }
  }
  #pragma unroll
  for (int i = 0; i < 4; ++i) {
    int obase = wid * 64 + i * 16 + (l >> 4) * 4;
    #pragma unroll
    for (int jt = 0; jt < 4; ++jt) {
      int pxo = jt * 16 + (l & 15);
      #pragma unroll
      for (int r = 0; r < 4; ++r) {
        int o = obase + r;
        out[(((size_t)b * 256 + o) * 64 + y) * 64 + pxo] = acc[i][jt][r] + bias[o];
      }
    }
  }
}

extern "C" void kernel_launch(void* const* d_in, const int* in_sizes, int n_in,
                              void* d_out, int out_size, void* d_ws, size_t ws_size,
                              hipStream_t stream) {
  const float* main_f = (const float*)d_in[0];
  const float* cond   = (const float*)d_in[1];
  const float* w1  = (const float*)d_in[2];
  const float* b1  = (const float*)d_in[3];
  const float* g1  = (const float*)d_in[4];
  const float* be1 = (const float*)d_in[5];
  const float* w2  = (const float*)d_in[6];
  const float* b2  = (const float*)d_in[7];
  const float* g2  = (const float*)d_in[8];
  const float* be2 = (const float*)d_in[9];
  const float* w3  = (const float*)d_in[10];
  const float* b3  = (const float*)d_in[11];
  const float* w4  = (const float*)d_in[12];
  const float* b4  = (const float*)d_in[13];
  const float* g3  = (const float*)d_in[14];
  const float* be3 = (const float*)d_in[15];
  const float* w_co  = (const float*)d_in[16];
  const float* b_co  = (const float*)d_in[17];
  const float* w_dcn = (const float*)d_in[18];
  const float* b_dcn = (const float*)d_in[19];

  float* out = (float*)d_out;
  float* warp_out = out;               // [8,256,64,64] f32
  float* offset_feat = out + 8388608;  // [8,256,64,64] f32

  short* ws = (short*)d_ws;
  short* mainbf = ws;                    // 8388608
  short* A      = mainbf + 8388608;      // 8388608
  short* Bb     = A + 8388608;           // 8388608
  short* cobuf  = Bb + 8388608;          // 8*216*4096 = 7077888
  short* wf1    = cobuf + 7077888;       // 16*8192 = 131072
  short* wf3    = wf1 + 131072;          // 8*8192  = 65536
  short* wf4    = wf3 + 65536;           // 72*8192 = 589824
  short* wfco   = wf4 + 589824;          // 589824
  short* wfdcn  = wfco + 589824;         // 589824

  auto cdiv = [](int a, int b) { return (a + b - 1) / b; };

  k_prep_w<<<cdiv(16 * 8192, TPB), TPB, 0, stream>>>(w1, wf1, 256, 512, 1, 16, 0);
  k_prep_w<<<cdiv(8 * 8192, TPB), TPB, 0, stream>>>(w3, wf3, 256, 256, 1, 8, 0);
  k_prep_w<<<cdiv(72 * 8192, TPB), TPB, 0, stream>>>(w4, wf4, 256, 256, 9, 72, 0);
  k_prep_w<<<cdiv(72 * 8192, TPB), TPB, 0, stream>>>(w_co, wfco, 216, 256, 9, 72, 0);
  k_prep_w<<<cdiv(72 * 8192, TPB), TPB, 0, stream>>>(w_dcn, wfdcn, 256, 256, 9, 72, 1);

  k_tobf16<<<cdiv(2097152, TPB), TPB, 0, stream>>>(main_f, mainbf, 2097152);
  k_upsample<<<cdiv(8 * 256 * 4096, TPB), TPB, 0, stream>>>(cond, A);

  dim3 gconv(64, 4, 8);
  // conv1: 1x1 concat(cond_up, main) 512->256
  k_conv_mfma<<<gconv, TPB, 0, stream>>>(A, mainbf, 256, 512, 256, 1, wf1, b1, Bb, nullptr);
  k_gn_silu_bf<<<256, TPB, 0, stream>>>(Bb, Bb, nullptr, g1, be1);
  dim3 gdw(256, 8);
  k_dwconv7<<<gdw, TPB, 0, stream>>>(Bb, w2, b2, A);
  k_gn_silu_bf<<<256, TPB, 0, stream>>>(A, A, nullptr, g2, be2);
  // conv3: 1x1 256->256
  k_conv_mfma<<<gconv, TPB, 0, stream>>>(A, nullptr, 256, 256, 256, 1, wf3, b3, Bb, nullptr);
  // conv4: 3x3 256->256
  k_conv_mfma<<<gconv, TPB, 0, stream>>>(Bb, nullptr, 256, 256, 256, 9, wf4, b4, A, nullptr);
  // GN3+SiLU -> offset_feat (f32 output) + bf16 copy in A
  k_gn_silu_bf<<<256, TPB, 0, stream>>>(A, A, offset_feat, g3, be3);
  // conv_offset: 3x3 256->216 -> co (bf16)
  k_conv_mfma<<<gconv, TPB, 0, stream>>>(A, nullptr, 256, 256, 216, 9, wfco, b_co, cobuf, nullptr);
  // deformable conv -> warp
  dim3 gdcn(64, 8);
  k_dcn_mfma<<<gdcn, TPB, 0, stream>>>(mainbf, cobuf, wfdcn, b_dcn, warp_out);
}

// Round 4
// 901.591 us; speedup vs baseline: 2.6056x; 1.1379x over previous
//
#include <hip/hip_runtime.h>
#include <cstdint>

#define TPB 256

typedef __attribute__((ext_vector_type(8))) short s16x8;
typedef __attribute__((ext_vector_type(4))) short s16x4;
typedef __attribute__((ext_vector_type(4))) float f32x4;

__device__ __forceinline__ float silu_f(float x) { return x / (1.f + __expf(-x)); }

__device__ __forceinline__ short f2bf(float f) {
  union { float f; unsigned u; } v; v.f = f;
  unsigned r = v.u + 0x7fffu + ((v.u >> 16) & 1u);
  return (short)(r >> 16);
}
__device__ __forceinline__ float bf2f(short s) {
  union { unsigned u; float f; } v;
  v.u = ((unsigned)(unsigned short)s) << 16;
  return v.f;
}

// Pre-arrange conv weights into MFMA A-fragment order (bf16).  (verified R3)
// dst elem ((q*16 + ot)*64 + l)*8 + j = bf16(w[o=ot*16+(l&15)][c=cb*32+((l>>4)&3)*8+j][tap])
// mode 0: q = tap*ncb + cb ; mode 1 (dcn): q = cb*9 + tap.
__global__ void k_prep_w(const float* __restrict__ w, short* __restrict__ dst,
                         int Cout, int Cin, int taps, int nq, int mode) {
  int idx = blockIdx.x * TPB + threadIdx.x;
  int total = nq * 16 * 64 * 8;
  if (idx >= total) return;
  int j = idx & 7;
  int l = (idx >> 3) & 63;
  int ot = (idx >> 9) & 15;
  int q = idx >> 13;
  int tap, cb;
  if (mode == 0) { int ncb = Cin >> 5; tap = q / ncb; cb = q - tap * ncb; }
  else           { tap = q % 9; cb = q / 9; }
  int o = ot * 16 + (l & 15);
  int c = cb * 32 + ((l >> 4) & 3) * 8 + j;
  float v = 0.f;
  if (o < Cout && c < Cin) v = w[((size_t)o * Cin + c) * taps + tap];
  dst[idx] = f2bf(v);
}

// bilinear 16x16 -> 64x64 (half-pixel, edge clamp), write NHWC-512 channels 0..255
__global__ void k_upsample_nhwc(const float* __restrict__ in, short* __restrict__ outA) {
  int idx = blockIdx.x * TPB + threadIdx.x;
  if (idx >= 8 * 4096 * 256) return;
  int c = idx & 255;
  int p = idx >> 8;          // (b*4096 + y*64 + x)
  int b = p >> 12;
  int rem = p & 4095;
  int y = rem >> 6, x = rem & 63;
  float sy = (y + 0.5f) * 0.25f - 0.5f;
  float sx = (x + 0.5f) * 0.25f - 0.5f;
  float y0f = floorf(sy), x0f = floorf(sx);
  float ly = sy - y0f, lx = sx - x0f;
  int y0 = (int)y0f, x0 = (int)x0f;
  int y0c = min(15, max(0, y0)), y1c = min(15, max(0, y0 + 1));
  int x0c = min(15, max(0, x0)), x1c = min(15, max(0, x0 + 1));
  const float* src = in + (size_t)(b * 256 + c) * 256;
  float v00 = src[y0c * 16 + x0c], v01 = src[y0c * 16 + x1c];
  float v10 = src[y1c * 16 + x0c], v11 = src[y1c * 16 + x1c];
  float r = (1.f - ly) * ((1.f - lx) * v00 + lx * v01)
          + ly * ((1.f - lx) * v10 + lx * v11);
  outA[(size_t)p * 512 + c] = f2bf(r);
}

// main f32 NCHW -> bf16 NHWC-256 (xbf) + NHWC-512 channels 256..511 (conv1 input)
__global__ void k_main_tr(const float* __restrict__ in, short* __restrict__ xbf,
                          short* __restrict__ outA) {
  int idx = blockIdx.x * TPB + threadIdx.x;
  if (idx >= 8 * 4096 * 256) return;
  int c = idx & 255;
  int p = idx >> 8;
  int b = p >> 12;
  int pix = p & 4095;
  short s = f2bf(in[(size_t)(b * 256 + c) * 4096 + pix]);
  xbf[(size_t)p * 256 + c] = s;
  outA[(size_t)p * 512 + 256 + c] = s;
}

// NHWC MFMA conv. Block (row y, 64-o group og, b), 4 waves 2x2 (o-half x px-half),
// wave = 32o x 32px via 2x2 tiles of 16x16x32. LDS [px(+halo)][256c] stride 264.
// taps = 1 or 9 (pad 1). remap=1: write channel-permuted NHWC-256 co layout.
__global__ __launch_bounds__(256) void k_conv_nhwc(
    const short* __restrict__ in, int Cin, int Cout, int taps,
    const short* __restrict__ wf, const float* __restrict__ bias,
    short* __restrict__ out, int remap) {
  const int y = blockIdx.x, og = blockIdx.y, b = blockIdx.z;
  const int t = threadIdx.x;
  const int wid = t >> 6, l = t & 63;
  const int wo = wid >> 1, wp = wid & 1;
  const int pd = (taps == 9) ? 1 : 0;
  const int rows = 64 + 2 * pd;
  const int ncb = Cin >> 5;
  __shared__ __align__(16) short s2[66 * 264];
  f32x4 acc[2][2];
  #pragma unroll
  for (int i = 0; i < 2; ++i)
    #pragma unroll
    for (int j = 0; j < 2; ++j) acc[i][j] = (f32x4){0.f, 0.f, 0.f, 0.f};
  const int ndx = (taps == 9) ? 3 : 1;
  for (int dy = -pd; dy <= pd; ++dy) {
    const int yin = y + dy;
    if (yin < 0 || yin >= 64) continue;  // zero-pad rows contribute 0
    for (int c0 = 0; c0 < Cin; c0 += 256) {
      __syncthreads();
      const int nun = rows * 32;  // s16x8 units to stage
      #pragma unroll
      for (int i = 0; i < 9; ++i) {
        int e = t + i * 256;
        if (e < nun) {
          int pxs = e >> 5, oct = e & 31;
          int pxin = pxs - pd;
          s16x8 v = {0, 0, 0, 0, 0, 0, 0, 0};
          if (pxin >= 0 && pxin < 64)
            v = *(const s16x8*)(in + (size_t)((b * 64 + yin) * 64 + pxin) * Cin
                                + c0 + oct * 8);
          *(s16x8*)(s2 + pxs * 264 + oct * 8) = v;
        }
      }
      __syncthreads();
      const int cbg0 = c0 >> 5;
      for (int cb = 0; cb < 8; ++cb) {
        for (int dxi = 0; dxi < ndx; ++dxi) {
          const int dx = (taps == 9) ? dxi - 1 : 0;
          const int tap = (taps == 9) ? (dy + 1) * 3 + (dx + 1) : 0;
          const int q = tap * ncb + cbg0 + cb;
          s16x8 afr[2], bfr[2];
          #pragma unroll
          for (int i = 0; i < 2; ++i) {
            int ot = og * 4 + wo * 2 + i;
            afr[i] = *(const s16x8*)(wf + (((size_t)q * 16 + ot) * 64 + l) * 8);
          }
          #pragma unroll
          for (int jt = 0; jt < 2; ++jt) {
            int px = wp * 32 + jt * 16 + (l & 15);
            bfr[jt] = *(const s16x8*)(s2 + (px + dx + pd) * 264 + cb * 32 + (l >> 4) * 8);
          }
          #pragma unroll
          for (int i = 0; i < 2; ++i)
            #pragma unroll
            for (int jt = 0; jt < 2; ++jt)
              acc[i][jt] = __builtin_amdgcn_mfma_f32_16x16x32_bf16(
                  afr[i], bfr[jt], acc[i][jt], 0, 0, 0);
        }
      }
    }
  }
  #pragma unroll
  for (int i = 0; i < 2; ++i) {
    #pragma unroll
    for (int jt = 0; jt < 2; ++jt) {
      int px = wp * 32 + jt * 16 + (l & 15);
      int obase = og * 64 + wo * 32 + i * 16 + (l >> 4) * 4;
      size_t pbase = (size_t)((b * 64 + y) * 64 + px) * (remap ? 256 : Cout);
      if (!remap) {
        s16x4 r;
        #pragma unroll
        for (int rr = 0; rr < 4; ++rr) r[rr] = f2bf(acc[i][jt][rr] + bias[obase + rr]);
        *(s16x4*)(out + pbase + obase) = r;
      } else {
        #pragma unroll
        for (int rr = 0; rr < 4; ++rr) {
          int o = obase + rr;
          if (o < Cout) {
            int op;
            if (o < 144) op = (o / 18) * 32 + (o % 18);
            else { int jj = o - 144; op = (jj / 9) * 32 + 18 + (jj % 9); }
            out[pbase + op] = f2bf(acc[i][jt][rr] + bias[o]);
          }
        }
      }
    }
  }
}

// GroupNorm(32, eps 1e-6) + SiLU on NHWC bf16 (in-place) + optional f32 NCHW out.
__global__ __launch_bounds__(256) void k_gn_nhwc(short* __restrict__ io,
    float* __restrict__ f32out, const float* __restrict__ gamma,
    const float* __restrict__ beta) {
  const int bg = blockIdx.x;
  const int b = bg >> 5, g = bg & 31;
  const int t = threadIdx.x;
  float s = 0.f, sq = 0.f;
  for (int e = t; e < 4096; e += TPB) {
    s16x8 v = *(const s16x8*)(io + (size_t)(b * 4096 + e) * 256 + g * 8);
    #pragma unroll
    for (int j = 0; j < 8; ++j) { float f = bf2f(v[j]); s += f; sq += f * f; }
  }
  #pragma unroll
  for (int off = 32; off > 0; off >>= 1) {
    s += __shfl_down(s, off);
    sq += __shfl_down(sq, off);
  }
  __shared__ float ps[4], pq[4];
  __shared__ float smv, srv;
  const int wv = t >> 6, lane = t & 63;
  if (lane == 0) { ps[wv] = s; pq[wv] = sq; }
  __syncthreads();
  if (t == 0) {
    float S = ps[0] + ps[1] + ps[2] + ps[3];
    float Q = pq[0] + pq[1] + pq[2] + pq[3];
    float mean = S * (1.f / 32768.f);
    float var = Q * (1.f / 32768.f) - mean * mean;
    smv = mean;
    srv = rsqrtf(var + 1e-6f);
  }
  __syncthreads();
  const float m = smv, rs = srv;
  float ga[8], bb[8];
  #pragma unroll
  for (int j = 0; j < 8; ++j) {
    ga[j] = gamma[g * 8 + j] * rs;
    bb[j] = beta[g * 8 + j] - m * ga[j];
  }
  for (int e = t; e < 4096; e += TPB) {
    short* ptr = io + (size_t)(b * 4096 + e) * 256 + g * 8;
    s16x8 v = *(const s16x8*)ptr;
    s16x8 r;
    #pragma unroll
    for (int j = 0; j < 8; ++j) {
      float o = silu_f(bf2f(v[j]) * ga[j] + bb[j]);
      r[j] = f2bf(o);
      if (f32out) f32out[(size_t)(b * 256 + g * 8 + j) * 4096 + e] = o;
    }
    *(s16x8*)ptr = r;
  }
}

// depthwise 7x7 pad 3, NHWC bf16, f32 math, weights cached in LDS [tap][256].
__global__ __launch_bounds__(256) void k_dw7_nhwc(const short* __restrict__ in,
    const float* __restrict__ w, const float* __restrict__ bias,
    short* __restrict__ out) {
  const int y = blockIdx.x, b = blockIdx.y;
  const int t = threadIdx.x;
  const int px = t & 63, q = t >> 6;
  __shared__ float wl[49 * 256];
  for (int e = t; e < 49 * 256; e += TPB) {
    int c = e & 255, tap = e >> 8;
    wl[tap * 256 + c] = w[c * 49 + tap];
  }
  __syncthreads();
  for (int gg = 0; gg < 8; ++gg) {
    const int ch = (q * 8 + gg) * 8;
    float4 b0 = *(const float4*)(bias + ch);
    float4 b1 = *(const float4*)(bias + ch + 4);
    float a[8] = {b0.x, b0.y, b0.z, b0.w, b1.x, b1.y, b1.z, b1.w};
    for (int ky = 0; ky < 7; ++ky) {
      int yy = y + ky - 3;
      if (yy < 0 || yy >= 64) continue;
      #pragma unroll
      for (int kx = 0; kx < 7; ++kx) {
        int xx = px + kx - 3;
        if (xx >= 0 && xx < 64) {
          s16x8 v = *(const s16x8*)(in + (size_t)((b * 64 + yy) * 64 + xx) * 256 + ch);
          const float4 w0 = *(const float4*)(wl + (ky * 7 + kx) * 256 + ch);
          const float4 w1 = *(const float4*)(wl + (ky * 7 + kx) * 256 + ch + 4);
          a[0] += bf2f(v[0]) * w0.x; a[1] += bf2f(v[1]) * w0.y;
          a[2] += bf2f(v[2]) * w0.z; a[3] += bf2f(v[3]) * w0.w;
          a[4] += bf2f(v[4]) * w1.x; a[5] += bf2f(v[5]) * w1.y;
          a[6] += bf2f(v[6]) * w1.z; a[7] += bf2f(v[7]) * w1.w;
        }
      }
    }
    s16x8 r;
    #pragma unroll
    for (int j = 0; j < 8; ++j) r[j] = f2bf(a[j]);
    *(s16x8*)(out + (size_t)((b * 64 + y) * 64 + px) * 256 + ch) = r;
  }
}

// Deformable conv v2 via MFMA, NHWC. Block (y, b); 4 waves; per group g:
// stage all 9 taps' samples (64px x 32ch) -> LDS, then 9 K-chunks of MFMA.
// co: channel-permuted NHWC-256 [px][g*32 + {0..17 off(y,x pairs), 18..26 mask}].
__global__ __launch_bounds__(256) void k_dcn_nhwc(const short* __restrict__ x,
    const short* __restrict__ co, const short* __restrict__ wf,
    const float* __restrict__ bias, float* __restrict__ out) {
  const int y = blockIdx.x, b = blockIdx.y;
  const int t = threadIdx.x;
  const int wid = t >> 6, l = t & 63;
  const int px = l, oct = wid;
  __shared__ __align__(16) short s2[9 * 64 * 40];
  f32x4 acc[4][4];
  #pragma unroll
  for (int i = 0; i < 4; ++i)
    #pragma unroll
    for (int j = 0; j < 4; ++j) acc[i][j] = (f32x4){0.f, 0.f, 0.f, 0.f};
  const short* xb = x + (size_t)b * 4096 * 256;
  for (int g = 0; g < 8; ++g) {
    __syncthreads();
    {
      const short* cp = co + (size_t)(b * 4096 + y * 64 + px) * 256 + g * 32;
      s16x8 v0 = *(const s16x8*)cp;
      s16x8 v1 = *(const s16x8*)(cp + 8);
      s16x8 v2 = *(const s16x8*)(cp + 16);
      s16x8 v3 = *(const s16x8*)(cp + 24);
      const int chb = g * 32 + oct * 8;
      #pragma unroll
      for (int k = 0; k < 9; ++k) {
        const int e0 = 2 * k, e1 = 2 * k + 1, em = 18 + k;
        float offy = bf2f(e0 < 8 ? v0[e0 & 7] : (e0 < 16 ? v1[e0 & 7] : v2[e0 & 7]));
        float offx = bf2f(e1 < 8 ? v0[e1 & 7] : (e1 < 16 ? v1[e1 & 7] : v2[e1 & 7]));
        float mlog = bf2f(em < 24 ? v2[em & 7] : v3[em & 7]);
        float mv = 1.f / (1.f + __expf(-mlog));
        float py = offy + (float)(y - 1 + k / 3);
        float pxf = offx + (float)(px - 1 + k % 3);
        float y0f = floorf(py), x0f = floorf(pxf);
        float ly = py - y0f, lx = pxf - x0f;
        int y0 = (int)y0f, x0 = (int)x0f;
        int y1 = y0 + 1, x1 = x0 + 1;
        float fy0 = (y0 >= 0 && y0 < 64) ? 1.f : 0.f;
        float fy1 = (y1 >= 0 && y1 < 64) ? 1.f : 0.f;
        float fx0 = (x0 >= 0 && x0 < 64) ? 1.f : 0.f;
        float fx1 = (x1 >= 0 && x1 < 64) ? 1.f : 0.f;
        float w00 = (1.f - ly) * (1.f - lx) * fy0 * fx0 * mv;
        float w01 = (1.f - ly) * lx * fy0 * fx1 * mv;
        float w10 = ly * (1.f - lx) * fy1 * fx0 * mv;
        float w11 = ly * lx * fy1 * fx1 * mv;
        int y0c = min(63, max(0, y0)), y1c = min(63, max(0, y1));
        int x0c = min(63, max(0, x0)), x1c = min(63, max(0, x1));
        const short* xc = xb + chb;
        s16x8 c00 = *(const s16x8*)(xc + (size_t)(y0c * 64 + x0c) * 256);
        s16x8 c01 = *(const s16x8*)(xc + (size_t)(y0c * 64 + x1c) * 256);
        s16x8 c10 = *(const s16x8*)(xc + (size_t)(y1c * 64 + x0c) * 256);
        s16x8 c11 = *(const s16x8*)(xc + (size_t)(y1c * 64 + x1c) * 256);
        s16x8 pk;
        #pragma unroll
        for (int cc = 0; cc < 8; ++cc) {
          float v = w00 * bf2f(c00[cc]) + w01 * bf2f(c01[cc])
                  + w10 * bf2f(c10[cc]) + w11 * bf2f(c11[cc]);
          pk[cc] = f2bf(v);
        }
        *(s16x8*)(s2 + (k * 64 + px) * 40 + oct * 8) = pk;
      }
    }
    __syncthreads();
    #pragma unroll
    for (int k = 0; k < 9; ++k) {
      const int q = g * 9 + k;
      s16x8 afr[4], bfr[4];
      #pragma unroll
      for (int i = 0; i < 4; ++i)
        afr[i] = *(const s16x8*)(wf + (((size_t)q * 16 + wid * 4 + i) * 64 + l) * 8);
      #pragma unroll
      for (int jt = 0; jt < 4; ++jt)
        bfr[jt] = *(const s16x8*)(s2 + (k * 64 + jt * 16 + (l & 15)) * 40 + (l >> 4) * 8);
      #pragma unroll
      for (int i = 0; i < 4; ++i)
        #pragma unroll
        for (int jt = 0; jt < 4; ++jt)
          acc[i][jt] = __builtin_amdgcn_mfma_f32_16x16x32_bf16(
              afr[i], bfr[jt], acc[i][jt], 0, 0, 0);
    }
  }
  #pragma unroll
  for (int i = 0; i < 4; ++i) {
    int obase = wid * 64 + i * 16 + (l >> 4) * 4;
    #pragma unroll
    for (int jt = 0; jt < 4; ++jt) {
      int pxo = jt * 16 + (l & 15);
      #pragma unroll
      for (int r = 0; r < 4; ++r) {
        int o = obase + r;
        out[(((size_t)b * 256 + o) * 64 + y) * 64 + pxo] = acc[i][jt][r] + bias[o];
      }
    }
  }
}

extern "C" void kernel_launch(void* const* d_in, const int* in_sizes, int n_in,
                              void* d_out, int out_size, void* d_ws, size_t ws_size,
                              hipStream_t stream) {
  const float* main_f = (const float*)d_in[0];
  const float* cond   = (const float*)d_in[1];
  const float* w1  = (const float*)d_in[2];
  const float* b1  = (const float*)d_in[3];
  const float* g1  = (const float*)d_in[4];
  const float* be1 = (const float*)d_in[5];
  const float* w2  = (const float*)d_in[6];
  const float* b2  = (const float*)d_in[7];
  const float* g2  = (const float*)d_in[8];
  const float* be2 = (const float*)d_in[9];
  const float* w3  = (const float*)d_in[10];
  const float* b3  = (const float*)d_in[11];
  const float* w4  = (const float*)d_in[12];
  const float* b4  = (const float*)d_in[13];
  const float* g3  = (const float*)d_in[14];
  const float* be3 = (const float*)d_in[15];
  const float* w_co  = (const float*)d_in[16];
  const float* b_co  = (const float*)d_in[17];
  const float* w_dcn = (const float*)d_in[18];
  const float* b_dcn = (const float*)d_in[19];

  float* out = (float*)d_out;
  float* warp_out = out;               // [8,256,64,64] f32 NCHW
  float* offset_feat = out + 8388608;  // [8,256,64,64] f32 NCHW

  short* ws = (short*)d_ws;
  short* bufA  = ws;                   // NHWC-512 conv1 input / later NHWC-256 reuse: 16777216
  short* Bb    = bufA + 16777216;      // NHWC-256: 8388608
  short* xbf   = Bb + 8388608;         // main NHWC-256 bf16: 8388608
  short* wf1   = xbf + 8388608;        // 16*8192 = 131072
  short* wf3   = wf1 + 131072;         // 8*8192  = 65536
  short* wf4   = wf3 + 65536;          // 72*8192 = 589824
  short* wfco  = wf4 + 589824;         // 589824
  short* wfdcn = wfco + 589824;        // 589824

  auto cdiv = [](int a, int b) { return (a + b - 1) / b; };

  k_prep_w<<<cdiv(16 * 8192, TPB), TPB, 0, stream>>>(w1, wf1, 256, 512, 1, 16, 0);
  k_prep_w<<<cdiv(8 * 8192, TPB), TPB, 0, stream>>>(w3, wf3, 256, 256, 1, 8, 0);
  k_prep_w<<<cdiv(72 * 8192, TPB), TPB, 0, stream>>>(w4, wf4, 256, 256, 9, 72, 0);
  k_prep_w<<<cdiv(72 * 8192, TPB), TPB, 0, stream>>>(w_co, wfco, 216, 256, 9, 72, 0);
  k_prep_w<<<cdiv(72 * 8192, TPB), TPB, 0, stream>>>(w_dcn, wfdcn, 256, 256, 9, 72, 1);

  k_upsample_nhwc<<<cdiv(8 * 4096 * 256, TPB), TPB, 0, stream>>>(cond, bufA);
  k_main_tr<<<cdiv(8 * 4096 * 256, TPB), TPB, 0, stream>>>(main_f, xbf, bufA);

  dim3 gconv(64, 4, 8);
  // conv1: 1x1 NHWC-512 -> NHWC-256
  k_conv_nhwc<<<gconv, TPB, 0, stream>>>(bufA, 512, 256, 1, wf1, b1, Bb, 0);
  k_gn_nhwc<<<256, TPB, 0, stream>>>(Bb, nullptr, g1, be1);
  dim3 gdw(64, 8);
  k_dw7_nhwc<<<gdw, TPB, 0, stream>>>(Bb, w2, b2, bufA);
  k_gn_nhwc<<<256, TPB, 0, stream>>>(bufA, nullptr, g2, be2);
  // conv3: 1x1
  k_conv_nhwc<<<gconv, TPB, 0, stream>>>(bufA, 256, 256, 1, wf3, b3, Bb, 0);
  // conv4: 3x3
  k_conv_nhwc<<<gconv, TPB, 0, stream>>>(Bb, 256, 256, 9, wf4, b4, bufA, 0);
  // GN3 + SiLU -> bf16 NHWC (in-place) + f32 NCHW offset_feat (output 1)
  k_gn_nhwc<<<256, TPB, 0, stream>>>(bufA, offset_feat, g3, be3);
  // conv_offset: 3x3 256->216, channel-permuted NHWC-256 co
  k_conv_nhwc<<<gconv, TPB, 0, stream>>>(bufA, 256, 216, 9, wfco, b_co, Bb, 1);
  // deformable conv -> warp (output 0)
  dim3 gdcn(64, 8);
  k_dcn_nhwc<<<gdcn, TPB, 0, stream>>>(xbf, Bb, wfdcn, b_dcn, warp_out);
}

// Round 6
// 710.502 us; speedup vs baseline: 3.3064x; 1.2690x over previous
//
#include <hip/hip_runtime.h>
#include <cstdint>

#define TPB 256

typedef __attribute__((ext_vector_type(8))) short s16x8;
typedef __attribute__((ext_vector_type(4))) short s16x4;
typedef __attribute__((ext_vector_type(4))) float f32x4;

__device__ __forceinline__ float silu_f(float x) { return x / (1.f + __expf(-x)); }

__device__ __forceinline__ short f2bf(float f) {
  union { float f; unsigned u; } v; v.f = f;
  unsigned r = v.u + 0x7fffu + ((v.u >> 16) & 1u);
  return (short)(r >> 16);
}
__device__ __forceinline__ float bf2f(short s) {
  union { unsigned u; float f; } v;
  v.u = ((unsigned)(unsigned short)s) << 16;
  return v.f;
}

// Pre-arrange conv weights into MFMA A-fragment order (bf16).  (verified R3)
// dst elem ((q*16 + ot)*64 + l)*8 + j = bf16(w[o=ot*16+(l&15)][c=cb*32+((l>>4)&3)*8+j][tap])
// mode 0: q = tap*ncb + cb ; mode 1 (dcn): q = cb*9 + tap.
__global__ void k_prep_w(const float* __restrict__ w, short* __restrict__ dst,
                         int Cout, int Cin, int taps, int nq, int mode) {
  int idx = blockIdx.x * TPB + threadIdx.x;
  int total = nq * 16 * 64 * 8;
  if (idx >= total) return;
  int j = idx & 7;
  int l = (idx >> 3) & 63;
  int ot = (idx >> 9) & 15;
  int q = idx >> 13;
  int tap, cb;
  if (mode == 0) { int ncb = Cin >> 5; tap = q / ncb; cb = q - tap * ncb; }
  else           { tap = q % 9; cb = q / 9; }
  int o = ot * 16 + (l & 15);
  int c = cb * 32 + ((l >> 4) & 3) * 8 + j;
  float v = 0.f;
  if (o < Cout && c < Cin) v = w[((size_t)o * Cin + c) * taps + tap];
  dst[idx] = f2bf(v);
}

// bilinear 16x16 -> 64x64 (half-pixel, edge clamp), write NHWC-512 channels 0..255
__global__ void k_upsample_nhwc(const float* __restrict__ in, short* __restrict__ outA) {
  int idx = blockIdx.x * TPB + threadIdx.x;
  if (idx >= 8 * 4096 * 256) return;
  int c = idx & 255;
  int p = idx >> 8;          // (b*4096 + y*64 + x)
  int b = p >> 12;
  int rem = p & 4095;
  int y = rem >> 6, x = rem & 63;
  float sy = (y + 0.5f) * 0.25f - 0.5f;
  float sx = (x + 0.5f) * 0.25f - 0.5f;
  float y0f = floorf(sy), x0f = floorf(sx);
  float ly = sy - y0f, lx = sx - x0f;
  int y0 = (int)y0f, x0 = (int)x0f;
  int y0c = min(15, max(0, y0)), y1c = min(15, max(0, y0 + 1));
  int x0c = min(15, max(0, x0)), x1c = min(15, max(0, x0 + 1));
  const float* src = in + (size_t)(b * 256 + c) * 256;
  float v00 = src[y0c * 16 + x0c], v01 = src[y0c * 16 + x1c];
  float v10 = src[y1c * 16 + x0c], v11 = src[y1c * 16 + x1c];
  float r = (1.f - ly) * ((1.f - lx) * v00 + lx * v01)
          + ly * ((1.f - lx) * v10 + lx * v11);
  outA[(size_t)p * 512 + c] = f2bf(r);
}

// main f32 NCHW -> bf16 NHWC-256 (xbf) + NHWC-512 channels 256..511 (conv1 input)
__global__ void k_main_tr(const float* __restrict__ in, short* __restrict__ xbf,
                          short* __restrict__ outA) {
  int idx = blockIdx.x * TPB + threadIdx.x;
  if (idx >= 8 * 4096 * 256) return;
  int c = idx & 255;
  int p = idx >> 8;
  int b = p >> 12;
  int pix = p & 4095;
  short s = f2bf(in[(size_t)(b * 256 + c) * 4096 + pix]);
  xbf[(size_t)p * 256 + c] = s;
  outA[(size_t)p * 512 + 256 + c] = s;
}

// NHWC MFMA conv. Block (row y, 64-o group og, b), 4 waves 2x2 (o-half x px-half),
// wave = 32o x 32px via 2x2 tiles of 16x16x32. LDS [px(+halo)][256c] stride 264.
// taps = 1 or 9 (pad 1). remap=1: write channel-permuted NHWC-256 co layout.
__global__ __launch_bounds__(256) void k_conv_nhwc(
    const short* __restrict__ in, int Cin, int Cout, int taps,
    const short* __restrict__ wf, const float* __restrict__ bias,
    short* __restrict__ out, int remap) {
  const int y = blockIdx.x, og = blockIdx.y, b = blockIdx.z;
  const int t = threadIdx.x;
  const int wid = t >> 6, l = t & 63;
  const int wo = wid >> 1, wp = wid & 1;
  const int pd = (taps == 9) ? 1 : 0;
  const int rows = 64 + 2 * pd;
  const int ncb = Cin >> 5;
  __shared__ __align__(16) short s2[66 * 264];
  f32x4 acc[2][2];
  #pragma unroll
  for (int i = 0; i < 2; ++i)
    #pragma unroll
    for (int j = 0; j < 2; ++j) acc[i][j] = (f32x4){0.f, 0.f, 0.f, 0.f};
  const int ndx = (taps == 9) ? 3 : 1;
  for (int dy = -pd; dy <= pd; ++dy) {
    const int yin = y + dy;
    if (yin < 0 || yin >= 64) continue;  // zero-pad rows contribute 0
    for (int c0 = 0; c0 < Cin; c0 += 256) {
      __syncthreads();
      const int nun = rows * 32;  // s16x8 units to stage
      #pragma unroll
      for (int i = 0; i < 9; ++i) {
        int e = t + i * 256;
        if (e < nun) {
          int pxs = e >> 5, oct = e & 31;
          int pxin = pxs - pd;
          s16x8 v = {0, 0, 0, 0, 0, 0, 0, 0};
          if (pxin >= 0 && pxin < 64)
            v = *(const s16x8*)(in + (size_t)((b * 64 + yin) * 64 + pxin) * Cin
                                + c0 + oct * 8);
          *(s16x8*)(s2 + pxs * 264 + oct * 8) = v;
        }
      }
      __syncthreads();
      const int cbg0 = c0 >> 5;
      for (int cb = 0; cb < 8; ++cb) {
        for (int dxi = 0; dxi < ndx; ++dxi) {
          const int dx = (taps == 9) ? dxi - 1 : 0;
          const int tap = (taps == 9) ? (dy + 1) * 3 + (dx + 1) : 0;
          const int q = tap * ncb + cbg0 + cb;
          s16x8 afr[2], bfr[2];
          #pragma unroll
          for (int i = 0; i < 2; ++i) {
            int ot = og * 4 + wo * 2 + i;
            afr[i] = *(const s16x8*)(wf + (((size_t)q * 16 + ot) * 64 + l) * 8);
          }
          #pragma unroll
          for (int jt = 0; jt < 2; ++jt) {
            int px = wp * 32 + jt * 16 + (l & 15);
            bfr[jt] = *(const s16x8*)(s2 + (px + dx + pd) * 264 + cb * 32 + (l >> 4) * 8);
          }
          #pragma unroll
          for (int i = 0; i < 2; ++i)
            #pragma unroll
            for (int jt = 0; jt < 2; ++jt)
              acc[i][jt] = __builtin_amdgcn_mfma_f32_16x16x32_bf16(
                  afr[i], bfr[jt], acc[i][jt], 0, 0, 0);
        }
      }
    }
  }
  #pragma unroll
  for (int i = 0; i < 2; ++i) {
    #pragma unroll
    for (int jt = 0; jt < 2; ++jt) {
      int px = wp * 32 + jt * 16 + (l & 15);
      int obase = og * 64 + wo * 32 + i * 16 + (l >> 4) * 4;
      size_t pbase = (size_t)((b * 64 + y) * 64 + px) * (remap ? 256 : Cout);
      if (!remap) {
        s16x4 r;
        #pragma unroll
        for (int rr = 0; rr < 4; ++rr) r[rr] = f2bf(acc[i][jt][rr] + bias[obase + rr]);
        *(s16x4*)(out + pbase + obase) = r;
      } else {
        #pragma unroll
        for (int rr = 0; rr < 4; ++rr) {
          int o = obase + rr;
          if (o < Cout) {
            int op;
            if (o < 144) op = (o / 18) * 32 + (o % 18);
            else { int jj = o - 144; op = (jj / 9) * 32 + 18 + (jj % 9); }
            out[pbase + op] = f2bf(acc[i][jt][rr] + bias[o]);
          }
        }
      }
    }
  }
}

// GroupNorm(32, eps 1e-6) + SiLU on NHWC bf16 (in-place) + optional f32 NCHW out.
__global__ __launch_bounds__(256) void k_gn_nhwc(short* __restrict__ io,
    float* __restrict__ f32out, const float* __restrict__ gamma,
    const float* __restrict__ beta) {
  const int bg = blockIdx.x;
  const int b = bg >> 5, g = bg & 31;
  const int t = threadIdx.x;
  float s = 0.f, sq = 0.f;
  for (int e = t; e < 4096; e += TPB) {
    s16x8 v = *(const s16x8*)(io + (size_t)(b * 4096 + e) * 256 + g * 8);
    #pragma unroll
    for (int j = 0; j < 8; ++j) { float f = bf2f(v[j]); s += f; sq += f * f; }
  }
  #pragma unroll
  for (int off = 32; off > 0; off >>= 1) {
    s += __shfl_down(s, off);
    sq += __shfl_down(sq, off);
  }
  __shared__ float ps[4], pq[4];
  __shared__ float smv, srv;
  const int wv = t >> 6, lane = t & 63;
  if (lane == 0) { ps[wv] = s; pq[wv] = sq; }
  __syncthreads();
  if (t == 0) {
    float S = ps[0] + ps[1] + ps[2] + ps[3];
    float Q = pq[0] + pq[1] + pq[2] + pq[3];
    float mean = S * (1.f / 32768.f);
    float var = Q * (1.f / 32768.f) - mean * mean;
    smv = mean;
    srv = rsqrtf(var + 1e-6f);
  }
  __syncthreads();
  const float m = smv, rs = srv;
  float ga[8], bb[8];
  #pragma unroll
  for (int j = 0; j < 8; ++j) {
    ga[j] = gamma[g * 8 + j] * rs;
    bb[j] = beta[g * 8 + j] - m * ga[j];
  }
  for (int e = t; e < 4096; e += TPB) {
    short* ptr = io + (size_t)(b * 4096 + e) * 256 + g * 8;
    s16x8 v = *(const s16x8*)ptr;
    s16x8 r;
    #pragma unroll
    for (int j = 0; j < 8; ++j) {
      float o = silu_f(bf2f(v[j]) * ga[j] + bb[j]);
      r[j] = f2bf(o);
      if (f32out) f32out[(size_t)(b * 256 + g * 8 + j) * 4096 + e] = o;
    }
    *(s16x8*)ptr = r;
  }
}

// depthwise 7x7 pad 3, NHWC bf16, LDS-staged tile version.
// Block = (ytile of 4 rows, 32-ch chunk, b). Stage 10 rows x 70 px x 32 ch bf16
// (px stride 40 shorts = 80B: 16B-aligned, bank-balanced) + 49x32 f32 weights.
// Threads: px = t&63, oc = t>>6 (4 octets of 8 ch). Each thread: 4 rows x 8 ch.
__global__ __launch_bounds__(256) void k_dw7_nhwc(const short* __restrict__ in,
    const float* __restrict__ w, const float* __restrict__ bias,
    short* __restrict__ out) {
  const int yt = blockIdx.x, ck = blockIdx.y, b = blockIdx.z;
  const int t = threadIdx.x;
  const int px = t & 63, oc = t >> 6;
  __shared__ __align__(16) short sl[10 * 70 * 40];
  __shared__ float wl[49 * 32];
  // stage weights [tap][cc]
  for (int e = t; e < 49 * 32; e += TPB) {
    int tap = e >> 5, cc = e & 31;
    wl[tap * 32 + cc] = w[(ck * 32 + cc) * 49 + tap];
  }
  // stage input patch: rows yt*4-3 .. yt*4+6, px -3..66, ch ck*32..+31
  const int y0in = yt * 4 - 3;
  #pragma unroll
  for (int i = 0; i < 11; ++i) {
    int e = t + i * TPB;
    if (e < 2800) {
      int oc2 = e & 3;
      int pe = e >> 2;
      int pxs = pe % 70;
      int row = pe / 70;
      int yy = y0in + row, xx = pxs - 3;
      s16x8 v = {0, 0, 0, 0, 0, 0, 0, 0};
      if (yy >= 0 && yy < 64 && xx >= 0 && xx < 64)
        v = *(const s16x8*)(in + (size_t)((b * 64 + yy) * 64 + xx) * 256
                            + ck * 32 + oc2 * 8);
      *(s16x8*)(sl + (row * 70 + pxs) * 40 + oc2 * 8) = v;
    }
  }
  __syncthreads();
  float acc[4][8];
  {
    float4 b0 = *(const float4*)(bias + ck * 32 + oc * 8);
    float4 b1 = *(const float4*)(bias + ck * 32 + oc * 8 + 4);
    #pragma unroll
    for (int r = 0; r < 4; ++r) {
      acc[r][0] = b0.x; acc[r][1] = b0.y; acc[r][2] = b0.z; acc[r][3] = b0.w;
      acc[r][4] = b1.x; acc[r][5] = b1.y; acc[r][6] = b1.z; acc[r][7] = b1.w;
    }
  }
  #pragma unroll
  for (int ky = 0; ky < 7; ++ky) {
    #pragma unroll
    for (int kx = 0; kx < 7; ++kx) {
      const float4 w0 = *(const float4*)(wl + (ky * 7 + kx) * 32 + oc * 8);
      const float4 w1 = *(const float4*)(wl + (ky * 7 + kx) * 32 + oc * 8 + 4);
      #pragma unroll
      for (int r = 0; r < 4; ++r) {
        s16x8 v = *(const s16x8*)(sl + ((r + ky) * 70 + (px + kx)) * 40 + oc * 8);
        acc[r][0] += bf2f(v[0]) * w0.x; acc[r][1] += bf2f(v[1]) * w0.y;
        acc[r][2] += bf2f(v[2]) * w0.z; acc[r][3] += bf2f(v[3]) * w0.w;
        acc[r][4] += bf2f(v[4]) * w1.x; acc[r][5] += bf2f(v[5]) * w1.y;
        acc[r][6] += bf2f(v[6]) * w1.z; acc[r][7] += bf2f(v[7]) * w1.w;
      }
    }
  }
  #pragma unroll
  for (int r = 0; r < 4; ++r) {
    int y = yt * 4 + r;
    s16x8 o;
    #pragma unroll
    for (int j = 0; j < 8; ++j) o[j] = f2bf(acc[r][j]);
    *(s16x8*)(out + (size_t)((b * 64 + y) * 64 + px) * 256 + ck * 32 + oc * 8) = o;
  }
}

// Deformable conv v2 via MFMA, NHWC. Block (y, b); 4 waves; per group g:
// stage all 9 taps' samples (64px x 32ch) -> LDS, then 9 K-chunks of MFMA.
// co: channel-permuted NHWC-256 [px][g*32 + {0..17 off(y,x pairs), 18..26 mask}].
__global__ __launch_bounds__(256) void k_dcn_nhwc(const short* __restrict__ x,
    const short* __restrict__ co, const short* __restrict__ wf,
    const float* __restrict__ bias, float* __restrict__ out) {
  const int y = blockIdx.x, b = blockIdx.y;
  const int t = threadIdx.x;
  const int wid = t >> 6, l = t & 63;
  const int px = l, oct = wid;
  __shared__ __align__(16) short s2[9 * 64 * 40];
  f32x4 acc[4][4];
  #pragma unroll
  for (int i = 0; i < 4; ++i)
    #pragma unroll
    for (int j = 0; j < 4; ++j) acc[i][j] = (f32x4){0.f, 0.f, 0.f, 0.f};
  const short* xb = x + (size_t)b * 4096 * 256;
  for (int g = 0; g < 8; ++g) {
    __syncthreads();
    {
      const short* cp = co + (size_t)(b * 4096 + y * 64 + px) * 256 + g * 32;
      s16x8 v0 = *(const s16x8*)cp;
      s16x8 v1 = *(const s16x8*)(cp + 8);
      s16x8 v2 = *(const s16x8*)(cp + 16);
      s16x8 v3 = *(const s16x8*)(cp + 24);
      const int chb = g * 32 + oct * 8;
      #pragma unroll
      for (int k = 0; k < 9; ++k) {
        const int e0 = 2 * k, e1 = 2 * k + 1, em = 18 + k;
        float offy = bf2f(e0 < 8 ? v0[e0 & 7] : (e0 < 16 ? v1[e0 & 7] : v2[e0 & 7]));
        float offx = bf2f(e1 < 8 ? v0[e1 & 7] : (e1 < 16 ? v1[e1 & 7] : v2[e1 & 7]));
        float mlog = bf2f(em < 24 ? v2[em & 7] : v3[em & 7]);
        float mv = 1.f / (1.f + __expf(-mlog));
        float py = offy + (float)(y - 1 + k / 3);
        float pxf = offx + (float)(px - 1 + k % 3);
        float y0f = floorf(py), x0f = floorf(pxf);
        float ly = py - y0f, lx = pxf - x0f;
        int y0 = (int)y0f, x0 = (int)x0f;
        int y1 = y0 + 1, x1 = x0 + 1;
        float fy0 = (y0 >= 0 && y0 < 64) ? 1.f : 0.f;
        float fy1 = (y1 >= 0 && y1 < 64) ? 1.f : 0.f;
        float fx0 = (x0 >= 0 && x0 < 64) ? 1.f : 0.f;
        float fx1 = (x1 >= 0 && x1 < 64) ? 1.f : 0.f;
        float w00 = (1.f - ly) * (1.f - lx) * fy0 * fx0 * mv;
        float w01 = (1.f - ly) * lx * fy0 * fx1 * mv;
        float w10 = ly * (1.f - lx) * fy1 * fx0 * mv;
        float w11 = ly * lx * fy1 * fx1 * mv;
        int y0c = min(63, max(0, y0)), y1c = min(63, max(0, y1));
        int x0c = min(63, max(0, x0)), x1c = min(63, max(0, x1));
        const short* xc = xb + chb;
        s16x8 c00 = *(const s16x8*)(xc + (size_t)(y0c * 64 + x0c) * 256);
        s16x8 c01 = *(const s16x8*)(xc + (size_t)(y0c * 64 + x1c) * 256);
        s16x8 c10 = *(const s16x8*)(xc + (size_t)(y1c * 64 + x0c) * 256);
        s16x8 c11 = *(const s16x8*)(xc + (size_t)(y1c * 64 + x1c) * 256);
        s16x8 pk;
        #pragma unroll
        for (int cc = 0; cc < 8; ++cc) {
          float v = w00 * bf2f(c00[cc]) + w01 * bf2f(c01[cc])
                  + w10 * bf2f(c10[cc]) + w11 * bf2f(c11[cc]);
          pk[cc] = f2bf(v);
        }
        *(s16x8*)(s2 + (k * 64 + px) * 40 + oct * 8) = pk;
      }
    }
    __syncthreads();
    #pragma unroll
    for (int k = 0; k < 9; ++k) {
      const int q = g * 9 + k;
      s16x8 afr[4], bfr[4];
      #pragma unroll
      for (int i = 0; i < 4; ++i)
        afr[i] = *(const s16x8*)(wf + (((size_t)q * 16 + wid * 4 + i) * 64 + l) * 8);
      #pragma unroll
      for (int jt = 0; jt < 4; ++jt)
        bfr[jt] = *(const s16x8*)(s2 + (k * 64 + jt * 16 + (l & 15)) * 40 + (l >> 4) * 8);
      #pragma unroll
      for (int i = 0; i < 4; ++i)
        #pragma unroll
        for (int jt = 0; jt < 4; ++jt)
          acc[i][jt] = __builtin_amdgcn_mfma_f32_16x16x32_bf16(
              afr[i], bfr[jt], acc[i][jt], 0, 0, 0);
    }
  }
  #pragma unroll
  for (int i = 0; i < 4; ++i) {
    int obase = wid * 64 + i * 16 + (l >> 4) * 4;
    #pragma unroll
    for (int jt = 0; jt < 4; ++jt) {
      int pxo = jt * 16 + (l & 15);
      #pragma unroll
      for (int r = 0; r < 4; ++r) {
        int o = obase + r;
        out[(((size_t)b * 256 + o) * 64 + y) * 64 + pxo] = acc[i][jt][r] + bias[o];
      }
    }
  }
}

extern "C" void kernel_launch(void* const* d_in, const int* in_sizes, int n_in,
                              void* d_out, int out_size, void* d_ws, size_t ws_size,
                              hipStream_t stream) {
  const float* main_f = (const float*)d_in[0];
  const float* cond   = (const float*)d_in[1];
  const float* w1  = (const float*)d_in[2];
  const float* b1  = (const float*)d_in[3];
  const float* g1  = (const float*)d_in[4];
  const float* be1 = (const float*)d_in[5];
  const float* w2  = (const float*)d_in[6];
  const float* b2  = (const float*)d_in[7];
  const float* g2  = (const float*)d_in[8];
  const float* be2 = (const float*)d_in[9];
  const float* w3  = (const float*)d_in[10];
  const float* b3  = (const float*)d_in[11];
  const float* w4  = (const float*)d_in[12];
  const float* b4  = (const float*)d_in[13];
  const float* g3  = (const float*)d_in[14];
  const float* be3 = (const float*)d_in[15];
  const float* w_co  = (const float*)d_in[16];
  const float* b_co  = (const float*)d_in[17];
  const float* w_dcn = (const float*)d_in[18];
  const float* b_dcn = (const float*)d_in[19];

  float* out = (float*)d_out;
  float* warp_out = out;               // [8,256,64,64] f32 NCHW
  float* offset_feat = out + 8388608;  // [8,256,64,64] f32 NCHW

  short* ws = (short*)d_ws;
  short* bufA  = ws;                   // NHWC-512 conv1 input / later NHWC-256 reuse: 16777216
  short* Bb    = bufA + 16777216;      // NHWC-256: 8388608
  short* xbf   = Bb + 8388608;         // main NHWC-256 bf16: 8388608
  short* wf1   = xbf + 8388608;        // 16*8192 = 131072
  short* wf3   = wf1 + 131072;         // 8*8192  = 65536
  short* wf4   = wf3 + 65536;          // 72*8192 = 589824
  short* wfco  = wf4 + 589824;         // 589824
  short* wfdcn = wfco + 589824;        // 589824

  auto cdiv = [](int a, int b) { return (a + b - 1) / b; };

  k_prep_w<<<cdiv(16 * 8192, TPB), TPB, 0, stream>>>(w1, wf1, 256, 512, 1, 16, 0);
  k_prep_w<<<cdiv(8 * 8192, TPB), TPB, 0, stream>>>(w3, wf3, 256, 256, 1, 8, 0);
  k_prep_w<<<cdiv(72 * 8192, TPB), TPB, 0, stream>>>(w4, wf4, 256, 256, 9, 72, 0);
  k_prep_w<<<cdiv(72 * 8192, TPB), TPB, 0, stream>>>(w_co, wfco, 216, 256, 9, 72, 0);
  k_prep_w<<<cdiv(72 * 8192, TPB), TPB, 0, stream>>>(w_dcn, wfdcn, 256, 256, 9, 72, 1);

  k_upsample_nhwc<<<cdiv(8 * 4096 * 256, TPB), TPB, 0, stream>>>(cond, bufA);
  k_main_tr<<<cdiv(8 * 4096 * 256, TPB), TPB, 0, stream>>>(main_f, xbf, bufA);

  dim3 gconv(64, 4, 8);
  // conv1: 1x1 NHWC-512 -> NHWC-256
  k_conv_nhwc<<<gconv, TPB, 0, stream>>>(bufA, 512, 256, 1, wf1, b1, Bb, 0);
  k_gn_nhwc<<<256, TPB, 0, stream>>>(Bb, nullptr, g1, be1);
  dim3 gdw(16, 8, 8);
  k_dw7_nhwc<<<gdw, TPB, 0, stream>>>(Bb, w2, b2, bufA);
  k_gn_nhwc<<<256, TPB, 0, stream>>>(bufA, nullptr, g2, be2);
  // conv3: 1x1
  k_conv_nhwc<<<gconv, TPB, 0, stream>>>(bufA, 256, 256, 1, wf3, b3, Bb, 0);
  // conv4: 3x3
  k_conv_nhwc<<<gconv, TPB, 0, stream>>>(Bb, 256, 256, 9, wf4, b4, bufA, 0);
  // GN3 + SiLU -> bf16 NHWC (in-place) + f32 NCHW offset_feat (output 1)
  k_gn_nhwc<<<256, TPB, 0, stream>>>(bufA, offset_feat, g3, be3);
  // conv_offset: 3x3 256->216, channel-permuted NHWC-256 co
  k_conv_nhwc<<<gconv, TPB, 0, stream>>>(bufA, 256, 216, 9, wfco, b_co, Bb, 1);
  // deformable conv -> warp (output 0)
  dim3 gdcn(64, 8);
  k_dcn_nhwc<<<gdcn, TPB, 0, stream>>>(xbf, Bb, wfdcn, b_dcn, warp_out);
}

// Round 7
// 648.259 us; speedup vs baseline: 3.6239x; 1.0960x over previous
//
#include <hip/hip_runtime.h>
#include <cstdint>

#define TPB 256
#define GNT 1024

typedef __attribute__((ext_vector_type(8))) short s16x8;
typedef __attribute__((ext_vector_type(4))) short s16x4;
typedef __attribute__((ext_vector_type(4))) float f32x4;

__device__ __forceinline__ float silu_f(float x) { return x / (1.f + __expf(-x)); }

__device__ __forceinline__ short f2bf(float f) {
  union { float f; unsigned u; } v; v.f = f;
  unsigned r = v.u + 0x7fffu + ((v.u >> 16) & 1u);
  return (short)(r >> 16);
}
__device__ __forceinline__ float bf2f(short s) {
  union { unsigned u; float f; } v;
  v.u = ((unsigned)(unsigned short)s) << 16;
  return v.f;
}

// Pre-arrange conv weights into MFMA A-fragment order (bf16).  (verified R3)
// dst elem ((q*16 + ot)*64 + l)*8 + j = bf16(w[o=ot*16+(l&15)][c=cb*32+((l>>4)&3)*8+j][tap])
// mode 0: q = tap*ncb + cb ; mode 1 (dcn): q = cb*9 + tap.
__global__ void k_prep_w(const float* __restrict__ w, short* __restrict__ dst,
                         int Cout, int Cin, int taps, int nq, int mode) {
  int idx = blockIdx.x * TPB + threadIdx.x;
  int total = nq * 16 * 64 * 8;
  if (idx >= total) return;
  int j = idx & 7;
  int l = (idx >> 3) & 63;
  int ot = (idx >> 9) & 15;
  int q = idx >> 13;
  int tap, cb;
  if (mode == 0) { int ncb = Cin >> 5; tap = q / ncb; cb = q - tap * ncb; }
  else           { tap = q % 9; cb = q / 9; }
  int o = ot * 16 + (l & 15);
  int c = cb * 32 + ((l >> 4) & 3) * 8 + j;
  float v = 0.f;
  if (o < Cout && c < Cin) v = w[((size_t)o * Cin + c) * taps + tap];
  dst[idx] = f2bf(v);
}

// bilinear 16x16 -> 64x64 (half-pixel, edge clamp), write NHWC-512 channels 0..255
__global__ void k_upsample_nhwc(const float* __restrict__ in, short* __restrict__ outA) {
  int idx = blockIdx.x * TPB + threadIdx.x;
  if (idx >= 8 * 4096 * 256) return;
  int c = idx & 255;
  int p = idx >> 8;          // (b*4096 + y*64 + x)
  int b = p >> 12;
  int rem = p & 4095;
  int y = rem >> 6, x = rem & 63;
  float sy = (y + 0.5f) * 0.25f - 0.5f;
  float sx = (x + 0.5f) * 0.25f - 0.5f;
  float y0f = floorf(sy), x0f = floorf(sx);
  float ly = sy - y0f, lx = sx - x0f;
  int y0 = (int)y0f, x0 = (int)x0f;
  int y0c = min(15, max(0, y0)), y1c = min(15, max(0, y0 + 1));
  int x0c = min(15, max(0, x0)), x1c = min(15, max(0, x0 + 1));
  const float* src = in + (size_t)(b * 256 + c) * 256;
  float v00 = src[y0c * 16 + x0c], v01 = src[y0c * 16 + x1c];
  float v10 = src[y1c * 16 + x0c], v11 = src[y1c * 16 + x1c];
  float r = (1.f - ly) * ((1.f - lx) * v00 + lx * v01)
          + ly * ((1.f - lx) * v10 + lx * v11);
  outA[(size_t)p * 512 + c] = f2bf(r);
}

// main f32 NCHW -> bf16 NHWC-256 (xbf) + NHWC-512 channels 256..511 (conv1 input)
__global__ void k_main_tr(const float* __restrict__ in, short* __restrict__ xbf,
                          short* __restrict__ outA) {
  int idx = blockIdx.x * TPB + threadIdx.x;
  if (idx >= 8 * 4096 * 256) return;
  int c = idx & 255;
  int p = idx >> 8;
  int b = p >> 12;
  int pix = p & 4095;
  short s = f2bf(in[(size_t)(b * 256 + c) * 4096 + pix]);
  xbf[(size_t)p * 256 + c] = s;
  outA[(size_t)p * 512 + 256 + c] = s;
}

// NHWC MFMA conv. Block (row y, 64-o group og, b), 4 waves 2x2 (o-half x px-half),
// wave = 32o x 32px via 2x2 tiles of 16x16x32. LDS [px(+halo)][256c] stride 264.
// taps = 1 or 9 (pad 1). remap=1: write channel-permuted NHWC-256 co layout.
__global__ __launch_bounds__(256) void k_conv_nhwc(
    const short* __restrict__ in, int Cin, int Cout, int taps,
    const short* __restrict__ wf, const float* __restrict__ bias,
    short* __restrict__ out, int remap) {
  const int y = blockIdx.x, og = blockIdx.y, b = blockIdx.z;
  const int t = threadIdx.x;
  const int wid = t >> 6, l = t & 63;
  const int wo = wid >> 1, wp = wid & 1;
  const int pd = (taps == 9) ? 1 : 0;
  const int rows = 64 + 2 * pd;
  const int ncb = Cin >> 5;
  __shared__ __align__(16) short s2[66 * 264];
  f32x4 acc[2][2];
  #pragma unroll
  for (int i = 0; i < 2; ++i)
    #pragma unroll
    for (int j = 0; j < 2; ++j) acc[i][j] = (f32x4){0.f, 0.f, 0.f, 0.f};
  const int ndx = (taps == 9) ? 3 : 1;
  for (int dy = -pd; dy <= pd; ++dy) {
    const int yin = y + dy;
    if (yin < 0 || yin >= 64) continue;  // zero-pad rows contribute 0
    for (int c0 = 0; c0 < Cin; c0 += 256) {
      __syncthreads();
      const int nun = rows * 32;  // s16x8 units to stage
      #pragma unroll
      for (int i = 0; i < 9; ++i) {
        int e = t + i * 256;
        if (e < nun) {
          int pxs = e >> 5, oct = e & 31;
          int pxin = pxs - pd;
          s16x8 v = {0, 0, 0, 0, 0, 0, 0, 0};
          if (pxin >= 0 && pxin < 64)
            v = *(const s16x8*)(in + (size_t)((b * 64 + yin) * 64 + pxin) * Cin
                                + c0 + oct * 8);
          *(s16x8*)(s2 + pxs * 264 + oct * 8) = v;
        }
      }
      __syncthreads();
      const int cbg0 = c0 >> 5;
      for (int cb = 0; cb < 8; ++cb) {
        for (int dxi = 0; dxi < ndx; ++dxi) {
          const int dx = (taps == 9) ? dxi - 1 : 0;
          const int tap = (taps == 9) ? (dy + 1) * 3 + (dx + 1) : 0;
          const int q = tap * ncb + cbg0 + cb;
          s16x8 afr[2], bfr[2];
          #pragma unroll
          for (int i = 0; i < 2; ++i) {
            int ot = og * 4 + wo * 2 + i;
            afr[i] = *(const s16x8*)(wf + (((size_t)q * 16 + ot) * 64 + l) * 8);
          }
          #pragma unroll
          for (int jt = 0; jt < 2; ++jt) {
            int px = wp * 32 + jt * 16 + (l & 15);
            bfr[jt] = *(const s16x8*)(s2 + (px + dx + pd) * 264 + cb * 32 + (l >> 4) * 8);
          }
          #pragma unroll
          for (int i = 0; i < 2; ++i)
            #pragma unroll
            for (int jt = 0; jt < 2; ++jt)
              acc[i][jt] = __builtin_amdgcn_mfma_f32_16x16x32_bf16(
                  afr[i], bfr[jt], acc[i][jt], 0, 0, 0);
        }
      }
    }
  }
  #pragma unroll
  for (int i = 0; i < 2; ++i) {
    #pragma unroll
    for (int jt = 0; jt < 2; ++jt) {
      int px = wp * 32 + jt * 16 + (l & 15);
      int obase = og * 64 + wo * 32 + i * 16 + (l >> 4) * 4;
      size_t pbase = (size_t)((b * 64 + y) * 64 + px) * (remap ? 256 : Cout);
      if (!remap) {
        s16x4 r;
        #pragma unroll
        for (int rr = 0; rr < 4; ++rr) r[rr] = f2bf(acc[i][jt][rr] + bias[obase + rr]);
        *(s16x4*)(out + pbase + obase) = r;
      } else {
        #pragma unroll
        for (int rr = 0; rr < 4; ++rr) {
          int o = obase + rr;
          if (o < Cout) {
            int op;
            if (o < 144) op = (o / 18) * 32 + (o % 18);
            else { int jj = o - 144; op = (jj / 9) * 32 + 18 + (jj % 9); }
            out[pbase + op] = f2bf(acc[i][jt][rr] + bias[o]);
          }
        }
      }
    }
  }
}

// GroupNorm(32, eps 1e-6) + SiLU on NHWC bf16 (in-place) + optional f32 NCHW out.
// 1024 threads (16 waves) per block; grid fixed at 256 blocks (b,g).
__global__ __launch_bounds__(1024) void k_gn_nhwc(short* __restrict__ io,
    float* __restrict__ f32out, const float* __restrict__ gamma,
    const float* __restrict__ beta) {
  const int bg = blockIdx.x;
  const int b = bg >> 5, g = bg & 31;
  const int t = threadIdx.x;
  float s = 0.f, sq = 0.f;
  for (int e = t; e < 4096; e += GNT) {
    s16x8 v = *(const s16x8*)(io + (size_t)(b * 4096 + e) * 256 + g * 8);
    #pragma unroll
    for (int j = 0; j < 8; ++j) { float f = bf2f(v[j]); s += f; sq += f * f; }
  }
  #pragma unroll
  for (int off = 32; off > 0; off >>= 1) {
    s += __shfl_down(s, off);
    sq += __shfl_down(sq, off);
  }
  __shared__ float ps[16], pq[16];
  __shared__ float smv, srv;
  const int wv = t >> 6, lane = t & 63;
  if (lane == 0) { ps[wv] = s; pq[wv] = sq; }
  __syncthreads();
  if (t == 0) {
    float S = 0.f, Q = 0.f;
    #pragma unroll
    for (int i = 0; i < 16; ++i) { S += ps[i]; Q += pq[i]; }
    float mean = S * (1.f / 32768.f);
    float var = Q * (1.f / 32768.f) - mean * mean;
    smv = mean;
    srv = rsqrtf(var + 1e-6f);
  }
  __syncthreads();
  const float m = smv, rs = srv;
  float ga[8], bb[8];
  #pragma unroll
  for (int j = 0; j < 8; ++j) {
    ga[j] = gamma[g * 8 + j] * rs;
    bb[j] = beta[g * 8 + j] - m * ga[j];
  }
  for (int e = t; e < 4096; e += GNT) {
    short* ptr = io + (size_t)(b * 4096 + e) * 256 + g * 8;
    s16x8 v = *(const s16x8*)ptr;
    s16x8 r;
    #pragma unroll
    for (int j = 0; j < 8; ++j) {
      float o = silu_f(bf2f(v[j]) * ga[j] + bb[j]);
      r[j] = f2bf(o);
      if (f32out) f32out[(size_t)(b * 256 + g * 8 + j) * 4096 + e] = o;
    }
    *(s16x8*)ptr = r;
  }
}

// depthwise 7x7 pad 3, NHWC bf16, LDS-staged tile version.
// Block = (ytile of 4 rows, 32-ch chunk, b). Stage 10 rows x 70 px x 32 ch bf16
// (px stride 40 shorts = 80B: 16B-aligned, bank-balanced) + 49x32 f32 weights.
// Threads: px = t&63, oc = t>>6 (4 octets of 8 ch). Each thread: 4 rows x 8 ch.
__global__ __launch_bounds__(256) void k_dw7_nhwc(const short* __restrict__ in,
    const float* __restrict__ w, const float* __restrict__ bias,
    short* __restrict__ out) {
  const int yt = blockIdx.x, ck = blockIdx.y, b = blockIdx.z;
  const int t = threadIdx.x;
  const int px = t & 63, oc = t >> 6;
  __shared__ __align__(16) short sl[10 * 70 * 40];
  __shared__ float wl[49 * 32];
  // stage weights [tap][cc]
  for (int e = t; e < 49 * 32; e += TPB) {
    int tap = e >> 5, cc = e & 31;
    wl[tap * 32 + cc] = w[(ck * 32 + cc) * 49 + tap];
  }
  // stage input patch: rows yt*4-3 .. yt*4+6, px -3..66, ch ck*32..+31
  const int y0in = yt * 4 - 3;
  #pragma unroll
  for (int i = 0; i < 11; ++i) {
    int e = t + i * TPB;
    if (e < 2800) {
      int oc2 = e & 3;
      int pe = e >> 2;
      int pxs = pe % 70;
      int row = pe / 70;
      int yy = y0in + row, xx = pxs - 3;
      s16x8 v = {0, 0, 0, 0, 0, 0, 0, 0};
      if (yy >= 0 && yy < 64 && xx >= 0 && xx < 64)
        v = *(const s16x8*)(in + (size_t)((b * 64 + yy) * 64 + xx) * 256
                            + ck * 32 + oc2 * 8);
      *(s16x8*)(sl + (row * 70 + pxs) * 40 + oc2 * 8) = v;
    }
  }
  __syncthreads();
  float acc[4][8];
  {
    float4 b0 = *(const float4*)(bias + ck * 32 + oc * 8);
    float4 b1 = *(const float4*)(bias + ck * 32 + oc * 8 + 4);
    #pragma unroll
    for (int r = 0; r < 4; ++r) {
      acc[r][0] = b0.x; acc[r][1] = b0.y; acc[r][2] = b0.z; acc[r][3] = b0.w;
      acc[r][4] = b1.x; acc[r][5] = b1.y; acc[r][6] = b1.z; acc[r][7] = b1.w;
    }
  }
  #pragma unroll
  for (int ky = 0; ky < 7; ++ky) {
    #pragma unroll
    for (int kx = 0; kx < 7; ++kx) {
      const float4 w0 = *(const float4*)(wl + (ky * 7 + kx) * 32 + oc * 8);
      const float4 w1 = *(const float4*)(wl + (ky * 7 + kx) * 32 + oc * 8 + 4);
      #pragma unroll
      for (int r = 0; r < 4; ++r) {
        s16x8 v = *(const s16x8*)(sl + ((r + ky) * 70 + (px + kx)) * 40 + oc * 8);
        acc[r][0] += bf2f(v[0]) * w0.x; acc[r][1] += bf2f(v[1]) * w0.y;
        acc[r][2] += bf2f(v[2]) * w0.z; acc[r][3] += bf2f(v[3]) * w0.w;
        acc[r][4] += bf2f(v[4]) * w1.x; acc[r][5] += bf2f(v[5]) * w1.y;
        acc[r][6] += bf2f(v[6]) * w1.z; acc[r][7] += bf2f(v[7]) * w1.w;
      }
    }
  }
  #pragma unroll
  for (int r = 0; r < 4; ++r) {
    int y = yt * 4 + r;
    s16x8 o;
    #pragma unroll
    for (int j = 0; j < 8; ++j) o[j] = f2bf(acc[r][j]);
    *(s16x8*)(out + (size_t)((b * 64 + y) * 64 + px) * 256 + ck * 32 + oc * 8) = o;
  }
}

// Deformable conv v2 via MFMA, NHWC, px-split.
// Block = (row y, px-half ph, b) -> 1024 blocks (4/CU). 4 waves, each 64o x 32px
// (4x2 tiles of 16x16). Per group g: sample 9 taps x 32px x 32ch -> LDS (23KB),
// then 9 K-chunks of MFMA. Sampling tasks decoded (oct,pxl,k), 4-lane-coalesced.
// co: channel-permuted NHWC-256 [px][g*32 + {0..17 off(y,x pairs), 18..26 mask}].
__global__ __launch_bounds__(256) void k_dcn_nhwc(const short* __restrict__ x,
    const short* __restrict__ co, const short* __restrict__ wf,
    const float* __restrict__ bias, float* __restrict__ out) {
  const int y = blockIdx.x, ph = blockIdx.y, b = blockIdx.z;
  const int t = threadIdx.x;
  const int wid = t >> 6, l = t & 63;
  const int px0 = ph * 32;
  __shared__ __align__(16) short s2[9 * 32 * 40];
  f32x4 acc[4][2];
  #pragma unroll
  for (int i = 0; i < 4; ++i)
    #pragma unroll
    for (int j = 0; j < 2; ++j) acc[i][j] = (f32x4){0.f, 0.f, 0.f, 0.f};
  const short* xb = x + (size_t)b * 4096 * 256;
  for (int g = 0; g < 8; ++g) {
    __syncthreads();
    // sampling: 1152 tasks = 4 oct x 32 px x 9 k
    #pragma unroll
    for (int i = 0; i < 5; ++i) {
      int e = t + i * 256;
      if (e < 1152) {
        int oct = e & 3, pxl = (e >> 2) & 31, k = e >> 7;
        int px = px0 + pxl;
        const short* cp = co + (size_t)(b * 4096 + y * 64 + px) * 256 + g * 32;
        float offy = bf2f(cp[2 * k]);
        float offx = bf2f(cp[2 * k + 1]);
        float mlog = bf2f(cp[18 + k]);
        float mv = 1.f / (1.f + __expf(-mlog));
        float py = offy + (float)(y - 1 + k / 3);
        float pxf = offx + (float)(px - 1 + k % 3);
        float y0f = floorf(py), x0f = floorf(pxf);
        float ly = py - y0f, lx = pxf - x0f;
        int y0 = (int)y0f, x0 = (int)x0f;
        int y1 = y0 + 1, x1 = x0 + 1;
        float fy0 = (y0 >= 0 && y0 < 64) ? 1.f : 0.f;
        float fy1 = (y1 >= 0 && y1 < 64) ? 1.f : 0.f;
        float fx0 = (x0 >= 0 && x0 < 64) ? 1.f : 0.f;
        float fx1 = (x1 >= 0 && x1 < 64) ? 1.f : 0.f;
        float w00 = (1.f - ly) * (1.f - lx) * fy0 * fx0 * mv;
        float w01 = (1.f - ly) * lx * fy0 * fx1 * mv;
        float w10 = ly * (1.f - lx) * fy1 * fx0 * mv;
        float w11 = ly * lx * fy1 * fx1 * mv;
        int y0c = min(63, max(0, y0)), y1c = min(63, max(0, y1));
        int x0c = min(63, max(0, x0)), x1c = min(63, max(0, x1));
        const short* xc = xb + g * 32 + oct * 8;
        s16x8 c00 = *(const s16x8*)(xc + (size_t)(y0c * 64 + x0c) * 256);
        s16x8 c01 = *(const s16x8*)(xc + (size_t)(y0c * 64 + x1c) * 256);
        s16x8 c10 = *(const s16x8*)(xc + (size_t)(y1c * 64 + x0c) * 256);
        s16x8 c11 = *(const s16x8*)(xc + (size_t)(y1c * 64 + x1c) * 256);
        s16x8 pk;
        #pragma unroll
        for (int cc = 0; cc < 8; ++cc) {
          float v = w00 * bf2f(c00[cc]) + w01 * bf2f(c01[cc])
                  + w10 * bf2f(c10[cc]) + w11 * bf2f(c11[cc]);
          pk[cc] = f2bf(v);
        }
        *(s16x8*)(s2 + (k * 32 + pxl) * 40 + oct * 8) = pk;
      }
    }
    __syncthreads();
    #pragma unroll
    for (int k = 0; k < 9; ++k) {
      const int q = g * 9 + k;
      s16x8 afr[4], bfr[2];
      #pragma unroll
      for (int i = 0; i < 4; ++i)
        afr[i] = *(const s16x8*)(wf + (((size_t)q * 16 + wid * 4 + i) * 64 + l) * 8);
      #pragma unroll
      for (int jt = 0; jt < 2; ++jt)
        bfr[jt] = *(const s16x8*)(s2 + (k * 32 + jt * 16 + (l & 15)) * 40 + (l >> 4) * 8);
      #pragma unroll
      for (int i = 0; i < 4; ++i)
        #pragma unroll
        for (int jt = 0; jt < 2; ++jt)
          acc[i][jt] = __builtin_amdgcn_mfma_f32_16x16x32_bf16(
              afr[i], bfr[jt], acc[i][jt], 0, 0, 0);
    }
  }
  #pragma unroll
  for (int i = 0; i < 4; ++i) {
    int obase = wid * 64 + i * 16 + (l >> 4) * 4;
    #pragma unroll
    for (int jt = 0; jt < 2; ++jt) {
      int pxo = px0 + jt * 16 + (l & 15);
      #pragma unroll
      for (int r = 0; r < 4; ++r) {
        int o = obase + r;
        out[(((size_t)b * 256 + o) * 64 + y) * 64 + pxo] = acc[i][jt][r] + bias[o];
      }
    }
  }
}

extern "C" void kernel_launch(void* const* d_in, const int* in_sizes, int n_in,
                              void* d_out, int out_size, void* d_ws, size_t ws_size,
                              hipStream_t stream) {
  const float* main_f = (const float*)d_in[0];
  const float* cond   = (const float*)d_in[1];
  const float* w1  = (const float*)d_in[2];
  const float* b1  = (const float*)d_in[3];
  const float* g1  = (const float*)d_in[4];
  const float* be1 = (const float*)d_in[5];
  const float* w2  = (const float*)d_in[6];
  const float* b2  = (const float*)d_in[7];
  const float* g2  = (const float*)d_in[8];
  const float* be2 = (const float*)d_in[9];
  const float* w3  = (const float*)d_in[10];
  const float* b3  = (const float*)d_in[11];
  const float* w4  = (const float*)d_in[12];
  const float* b4  = (const float*)d_in[13];
  const float* g3  = (const float*)d_in[14];
  const float* be3 = (const float*)d_in[15];
  const float* w_co  = (const float*)d_in[16];
  const float* b_co  = (const float*)d_in[17];
  const float* w_dcn = (const float*)d_in[18];
  const float* b_dcn = (const float*)d_in[19];

  float* out = (float*)d_out;
  float* warp_out = out;               // [8,256,64,64] f32 NCHW
  float* offset_feat = out + 8388608;  // [8,256,64,64] f32 NCHW

  short* ws = (short*)d_ws;
  short* bufA  = ws;                   // NHWC-512 conv1 input / later NHWC-256 reuse: 16777216
  short* Bb    = bufA + 16777216;      // NHWC-256: 8388608
  short* xbf   = Bb + 8388608;         // main NHWC-256 bf16: 8388608
  short* wf1   = xbf + 8388608;        // 16*8192 = 131072
  short* wf3   = wf1 + 131072;         // 8*8192  = 65536
  short* wf4   = wf3 + 65536;          // 72*8192 = 589824
  short* wfco  = wf4 + 589824;         // 589824
  short* wfdcn = wfco + 589824;        // 589824

  auto cdiv = [](int a, int b) { return (a + b - 1) / b; };

  k_prep_w<<<cdiv(16 * 8192, TPB), TPB, 0, stream>>>(w1, wf1, 256, 512, 1, 16, 0);
  k_prep_w<<<cdiv(8 * 8192, TPB), TPB, 0, stream>>>(w3, wf3, 256, 256, 1, 8, 0);
  k_prep_w<<<cdiv(72 * 8192, TPB), TPB, 0, stream>>>(w4, wf4, 256, 256, 9, 72, 0);
  k_prep_w<<<cdiv(72 * 8192, TPB), TPB, 0, stream>>>(w_co, wfco, 216, 256, 9, 72, 0);
  k_prep_w<<<cdiv(72 * 8192, TPB), TPB, 0, stream>>>(w_dcn, wfdcn, 256, 256, 9, 72, 1);

  k_upsample_nhwc<<<cdiv(8 * 4096 * 256, TPB), TPB, 0, stream>>>(cond, bufA);
  k_main_tr<<<cdiv(8 * 4096 * 256, TPB), TPB, 0, stream>>>(main_f, xbf, bufA);

  dim3 gconv(64, 4, 8);
  // conv1: 1x1 NHWC-512 -> NHWC-256
  k_conv_nhwc<<<gconv, TPB, 0, stream>>>(bufA, 512, 256, 1, wf1, b1, Bb, 0);
  k_gn_nhwc<<<256, GNT, 0, stream>>>(Bb, nullptr, g1, be1);
  dim3 gdw(16, 8, 8);
  k_dw7_nhwc<<<gdw, TPB, 0, stream>>>(Bb, w2, b2, bufA);
  k_gn_nhwc<<<256, GNT, 0, stream>>>(bufA, nullptr, g2, be2);
  // conv3: 1x1
  k_conv_nhwc<<<gconv, TPB, 0, stream>>>(bufA, 256, 256, 1, wf3, b3, Bb, 0);
  // conv4: 3x3
  k_conv_nhwc<<<gconv, TPB, 0, stream>>>(Bb, 256, 256, 9, wf4, b4, bufA, 0);
  // GN3 + SiLU -> bf16 NHWC (in-place) + f32 NCHW offset_feat (output 1)
  k_gn_nhwc<<<256, GNT, 0, stream>>>(bufA, offset_feat, g3, be3);
  // conv_offset: 3x3 256->216, channel-permuted NHWC-256 co
  k_conv_nhwc<<<gconv, TPB, 0, stream>>>(bufA, 256, 216, 9, wfco, b_co, Bb, 1);
  // deformable conv -> warp (output 0)
  dim3 gdcn(64, 2, 8);
  k_dcn_nhwc<<<gdcn, TPB, 0, stream>>>(xbf, Bb, wfdcn, b_dcn, warp_out);
}